// Round 20
// baseline (2484.906 us; speedup 1.0000x reference)
//
#include <hip/hip_runtime.h>
#include <hip/hip_bf16.h>

// ---------------------------------------------------------------------------
// BigBird forward. bf16 A/B GEMMs: per-shape {BM, TN, NBUF}; TN=256 for
// QKV/FF1 (16 MFMA/iter); residual-add fused into Wo/FF2 epilogue.
// ONE barrier/iter, m-fastest + bijective XCD swizzle. Attention: K dbuf +
// stage-1-ahead counted vmcnt, 2 barriers per kv-block.
// ---------------------------------------------------------------------------

#define S_LEN 2048
#define DMODEL 768
#define FFDIM 3072
#define VOCAB 50358
#define VPAD  50432
#define NLAYER 12
#define NHEAD 12
#define NB 32
#define NKB 8
#define QKVN 2304

typedef __attribute__((ext_vector_type(8))) short bfrag8;
typedef __attribute__((ext_vector_type(8))) unsigned short us8;
typedef __attribute__((ext_vector_type(4))) float facc4;

__device__ __forceinline__ unsigned short f2bf(float f) {
  unsigned int u = __builtin_bit_cast(unsigned int, f);
  u += 0x7fffu + ((u >> 16) & 1u);
  return (unsigned short)(u >> 16);
}
__device__ __forceinline__ float bf2f(unsigned short h) {
  unsigned int u = ((unsigned int)h) << 16;
  return __builtin_bit_cast(float, u);
}

#define MFMA16(a, b, c) __builtin_amdgcn_mfma_f32_16x16x32_bf16((a), (b), (c), 0, 0, 0)
#define GLDS16(g, l) __builtin_amdgcn_global_load_lds( \
    (const __attribute__((address_space(1))) void*)(g), \
    (__attribute__((address_space(3))) void*)(l), 16, 0, 0)

// ---------------------------------------------------------------------------
// numpy RNG replication (validated: passes)
// ---------------------------------------------------------------------------
struct Pcg {
  unsigned long long hi, lo, inc_hi, inc_lo;
  int has32; unsigned int buf32;
};

__device__ __forceinline__ void pcg_step(Pcg& p) {
  const unsigned long long MH = 0x2360ed051fc65da4ull;
  const unsigned long long ML = 0x4385df649fccf645ull;
  unsigned long long rl = p.lo * ML;
  unsigned long long rh = __umul64hi(p.lo, ML) + p.lo * MH + p.hi * ML;
  unsigned long long nl = rl + p.inc_lo;
  unsigned long long nh = rh + p.inc_hi + (nl < rl ? 1ull : 0ull);
  p.lo = nl; p.hi = nh;
}
__device__ __forceinline__ unsigned long long pcg_next64(Pcg& p) {
  pcg_step(p);
  unsigned int rot = (unsigned int)(p.hi >> 58);
  unsigned long long x = p.hi ^ p.lo;
  return (x >> rot) | (x << ((64u - rot) & 63u));
}
__device__ __forceinline__ unsigned int pcg_next32(Pcg& p) {
  if (p.has32) { p.has32 = 0; return p.buf32; }
  unsigned long long n = pcg_next64(p);
  p.has32 = 1; p.buf32 = (unsigned int)(n >> 32);
  return (unsigned int)n;
}
__device__ __forceinline__ unsigned int lemire32(Pcg& p, unsigned int rng) {
  unsigned int rng_excl = rng + 1u;
  unsigned long long m = (unsigned long long)pcg_next32(p) * (unsigned long long)rng_excl;
  unsigned int leftover = (unsigned int)m;
  if (leftover < rng_excl) {
    unsigned int threshold = (0xffffffffu - rng) % rng_excl;
    while (leftover < threshold) {
      m = (unsigned long long)pcg_next32(p) * (unsigned long long)rng_excl;
      leftover = (unsigned int)m;
    }
  }
  return (unsigned int)(m >> 32);
}

__global__ void blockmap_kernel(int* __restrict__ blk_idx, float* __restrict__ dedup) {
  if (threadIdx.x != 0 || blockIdx.x != 0) return;
  unsigned int pool[4];
  unsigned int hc = 0x43b0d7e5u;
  auto ss_hash = [&hc](unsigned int val) {
    val ^= hc; hc *= 0x931e8875u; val *= hc; val ^= val >> 16; return val;
  };
  auto ss_mix = [](unsigned int x, unsigned int y) {
    unsigned int r = 0xca01f9ddu * x - 0x4973f715u * y;
    r ^= r >> 16; return r;
  };
  for (int i = 0; i < 4; ++i) pool[i] = ss_hash(0u);
  for (int s = 0; s < 4; ++s)
    for (int d = 0; d < 4; ++d)
      if (s != d) pool[d] = ss_mix(pool[d], ss_hash(pool[s]));
  unsigned int st32[8];
  unsigned int hb = 0x8b51f9ddu;
  for (int i = 0; i < 8; ++i) {
    unsigned int dv = pool[i & 3];
    dv ^= hb; hb *= 0x58f38dedu; dv *= hb; dv ^= dv >> 16;
    st32[i] = dv;
  }
  unsigned long long sd[4];
  for (int i = 0; i < 4; ++i)
    sd[i] = (unsigned long long)st32[2*i] | ((unsigned long long)st32[2*i+1] << 32);
  Pcg p;
  p.inc_hi = (sd[2] << 1) | (sd[3] >> 63);
  p.inc_lo = (sd[3] << 1) | 1ull;
  p.hi = 0ull; p.lo = 0ull;
  pcg_step(p);
  unsigned long long ol = p.lo;
  p.lo = ol + sd[1];
  p.hi = p.hi + sd[0] + (p.lo < ol ? 1ull : 0ull);
  pcg_step(p);
  p.has32 = 0; p.buf32 = 0;

  for (int i = 0; i < NB; ++i) {
    int lst[8];
    lst[0] = 0; lst[1] = NB - 1;
    lst[2] = (i > 0) ? i - 1 : 0;
    lst[3] = i;
    lst[4] = (i + 1 < NB - 1) ? i + 1 : NB - 1;
    bool excl[NB];
    for (int c = 0; c < NB; ++c) excl[c] = false;
    for (int j = 0; j < 5; ++j) excl[lst[j]] = true;
    int cand[NB], n = 0;
    for (int c = 0; c < NB; ++c) if (!excl[c]) cand[n++] = c;
    long long idx[3];
    unsigned long long hs[4] = {~0ull, ~0ull, ~0ull, ~0ull};
    for (int tI = 0; tI < 3; ++tI) {
      unsigned long long j = (unsigned long long)(n - 3 + tI);
      unsigned long long val = (unsigned long long)lemire32(p, (unsigned int)j);
      unsigned long long loc = val & 3ull;
      while (hs[loc] != ~0ull && hs[loc] != val) loc = (loc + 1ull) & 3ull;
      if (hs[loc] == ~0ull) { hs[loc] = val; idx[tI] = (long long)val; }
      else {
        loc = j & 3ull;
        while (hs[loc] != ~0ull) loc = (loc + 1ull) & 3ull;
        hs[loc] = j; idx[tI] = (long long)j;
      }
    }
    for (int fi = 2; fi >= 1; --fi) {
      int fj = (int)lemire32(p, (unsigned int)fi);
      long long tmpv = idx[fi]; idx[fi] = idx[fj]; idx[fj] = tmpv;
    }
    lst[5] = cand[idx[0]]; lst[6] = cand[idx[1]]; lst[7] = cand[idx[2]];

    unsigned int seen = 0u;
    for (int j = 0; j < 8; ++j) {
      blk_idx[i*8 + j] = lst[j];
      dedup[i*8 + j] = ((seen >> lst[j]) & 1u) ? 0.0f : 1.0f;
      seen |= (1u << lst[j]);
    }
  }
}

// ---------------------------------------------------------------------------
// Weight transpose+convert: src f32 [K][N] -> dst bf16 [Npad][K]
// ---------------------------------------------------------------------------
__global__ __launch_bounds__(256) void tconv_kernel(
    const float* __restrict__ src, unsigned short* __restrict__ dst,
    int K, int N, size_t src_stride, size_t dst_stride) {
  __shared__ float tile[64][65];
  src += (size_t)blockIdx.z * src_stride;
  dst += (size_t)blockIdx.z * dst_stride;
  int n0 = blockIdx.x * 64, k0 = blockIdx.y * 64;
  int t = threadIdx.x;
  int tr = t >> 4, tc = (t & 15) * 4;
  if ((N & 3) == 0 && n0 + 64 <= N) {
    #pragma unroll
    for (int i = 0; i < 4; ++i) {
      int k = k0 + tr + i * 16;
      float4 v = *reinterpret_cast<const float4*>(src + (size_t)k * N + n0 + tc);
      tile[tr + i*16][tc + 0] = v.x; tile[tr + i*16][tc + 1] = v.y;
      tile[tr + i*16][tc + 2] = v.z; tile[tr + i*16][tc + 3] = v.w;
    }
  } else if ((N & 1) == 0 && n0 + 64 <= N) {
    #pragma unroll
    for (int i = 0; i < 4; ++i) {
      int k = k0 + tr + i * 16;
      float2 v0 = *reinterpret_cast<const float2*>(src + (size_t)k * N + n0 + tc);
      float2 v1 = *reinterpret_cast<const float2*>(src + (size_t)k * N + n0 + tc + 2);
      tile[tr + i*16][tc + 0] = v0.x; tile[tr + i*16][tc + 1] = v0.y;
      tile[tr + i*16][tc + 2] = v1.x; tile[tr + i*16][tc + 3] = v1.y;
    }
  } else {
    for (int i = 0; i < 4; ++i) {
      int k = k0 + tr + i * 16;
      #pragma unroll
      for (int q2 = 0; q2 < 4; ++q2) {
        int n = n0 + tc + q2;
        tile[tr + i*16][tc + q2] = (n < N) ? src[(size_t)k * N + n] : 0.0f;
      }
    }
  }
  __syncthreads();
  int wr_ = t >> 2, wc_ = (t & 3) * 16;
  us8 w0, w1;
  #pragma unroll
  for (int j = 0; j < 8; ++j) {
    w0[j] = f2bf(tile[wc_ + j][wr_]);
    w1[j] = f2bf(tile[wc_ + 8 + j][wr_]);
  }
  size_t b = (size_t)(n0 + wr_) * K + k0 + wc_;
  *reinterpret_cast<us8*>(dst + b) = w0;
  *reinterpret_cast<us8*>(dst + b + 8) = w1;
}

__global__ void bias_cat_kernel(const float* __restrict__ bq, const float* __restrict__ bk,
                                const float* __restrict__ bv, float* __restrict__ dst) {
  int l = blockIdx.x;
  for (int i = threadIdx.x; i < QKVN; i += blockDim.x) {
    float v = (i < 768) ? bq[l*768 + i] : (i < 1536) ? bk[l*768 + i - 768] : bv[l*768 + i - 1536];
    dst[l*QKVN + i] = v;
  }
}

// ---------------------------------------------------------------------------
// LayerNorm
// ---------------------------------------------------------------------------
__device__ __forceinline__ float block_sum256(float v, float* red) {
  for (int off = 32; off > 0; off >>= 1) v += __shfl_down(v, off);
  int wv = threadIdx.x >> 6;
  if ((threadIdx.x & 63) == 0) red[wv] = v;
  __syncthreads();
  float r = red[0] + red[1] + red[2] + red[3];
  __syncthreads();
  return r;
}

__global__ void embed_ln_kernel(const int* __restrict__ ids, const int* __restrict__ tts,
                                const float* __restrict__ we, const float* __restrict__ pe,
                                const float* __restrict__ te, const float* __restrict__ lns,
                                const float* __restrict__ lnb, float* __restrict__ x,
                                unsigned short* __restrict__ xh) {
  __shared__ float red[4];
  int row = blockIdx.x, t = threadIdx.x;
  int id = ids[row], ty = tts[row];
  float e[3]; float s = 0.0f;
  for (int j = 0; j < 3; ++j) {
    int d = t + 256*j;
    e[j] = we[(size_t)id*DMODEL + d] + pe[(size_t)row*DMODEL + d] + te[(size_t)ty*DMODEL + d];
    s += e[j];
  }
  float mean = block_sum256(s, red) * (1.0f/768.0f);
  float vs = 0.0f;
  for (int j = 0; j < 3; ++j) { float dd = e[j] - mean; vs += dd*dd; }
  float var = block_sum256(vs, red) * (1.0f/768.0f);
  float inv = rsqrtf(var + 1e-12f);
  for (int j = 0; j < 3; ++j) {
    int d = t + 256*j;
    float val = (e[j] - mean) * inv * lns[d] + lnb[d];
    size_t idx = (size_t)row*DMODEL + d;
    x[idx] = val;
    xh[idx] = f2bf(val);
  }
}

// resln v2: input a already holds residual+output sum (fused in GEMM epilogue)
__global__ void resln_kernel(float* __restrict__ x, const float* __restrict__ a,
                             const float* __restrict__ lns, const float* __restrict__ lnb,
                             unsigned short* __restrict__ xh) {
  __shared__ float red[4];
  int row = blockIdx.x, t = threadIdx.x;
  float e[3]; float s = 0.0f;
  for (int j = 0; j < 3; ++j) {
    int d = t + 256*j;
    e[j] = a[(size_t)row*DMODEL + d];
    s += e[j];
  }
  float mean = block_sum256(s, red) * (1.0f/768.0f);
  float vs = 0.0f;
  for (int j = 0; j < 3; ++j) { float dd = e[j] - mean; vs += dd*dd; }
  float var = block_sum256(vs, red) * (1.0f/768.0f);
  float inv = rsqrtf(var + 1e-12f);
  for (int j = 0; j < 3; ++j) {
    int d = t + 256*j;
    float val = (e[j] - mean) * inv * lns[d] + lnb[d];
    size_t idx = (size_t)row*DMODEL + d;
    x[idx] = val;
    xh[idx] = f2bf(val);
  }
}

// ---------------------------------------------------------------------------
// GEMM v14: bf16 A x bf16 B^T. Templated BM {64,128}, NBUF {3,4},
// TN {64,128,256}, RES (fuse residual add, OMODE==0 only).
// ONE barrier per k-iter. m-fastest + bijective XCD-chunk swizzle.
// ---------------------------------------------------------------------------
template<int BM, int NBUF, int TN, int OMODE, int ACT, int RES>
__global__ __launch_bounds__(256) void gemm14_kernel(
    const unsigned short* __restrict__ A_g, const unsigned short* __restrict__ Bt,
    const float* __restrict__ bias, const float* __restrict__ Rf,
    float* __restrict__ Cf, unsigned short* __restrict__ Ch,
    int K, int Nreal) {
  __shared__ alignas(16) unsigned short As[NBUF][BM][32];
  __shared__ alignas(16) unsigned short Bs[NBUF][TN][32];
  constexpr int MFR = BM / 32;
  constexpr int NFR = TN / 32;
  constexpr int ACALLS = BM / 64;
  constexpr int BCALLS = TN / 64;
  constexpr int NLOADS = ACALLS + BCALLS;
  constexpr int DEPTH = NBUF - 2;
  int t = threadIdx.x;
  int mb = (int)gridDim.x;
  int nwg = mb * (int)gridDim.y;
  int lin = (int)blockIdx.x + mb * (int)blockIdx.y;
  int cpx = nwg >> 3;
  int nl = (lin & 7) * cpx + (lin >> 3);
  int m0 = (nl % mb) * BM, n0 = (nl / mb) * TN;

  int wave = t >> 6, lane = t & 63, l16 = lane & 15, lk = lane >> 4;
  int wr = wave >> 1, wc = wave & 1;
  int row16 = lane >> 2, seg4 = lane & 3;
  const int srcoff = (seg4 ^ ((row16 >> 1) & 3)) * 8;
  const int swzrd = (lk ^ ((l16 >> 1) & 3)) * 8;

  const unsigned short* ag = A_g + (size_t)(m0 + wave*(BM/4) + row16) * K + srcoff;
  const unsigned short* bg = Bt + (size_t)(n0 + wave*(TN/4) + row16) * K + srcoff;
  const size_t K16 = (size_t)16 * K;

  auto STAGE = [&](int buf, int kit) {
    int k0 = kit << 5;
    #pragma unroll
    for (int j = 0; j < ACALLS; ++j)
      GLDS16(ag + (size_t)j * K16 + k0, &As[buf][wave*(BM/4) + 16*j][0]);
    #pragma unroll
    for (int j = 0; j < BCALLS; ++j)
      GLDS16(bg + (size_t)j * K16 + k0, &Bs[buf][wave*(TN/4) + 16*j][0]);
  };

  facc4 acc[MFR][NFR];
  #pragma unroll
  for (int mi = 0; mi < MFR; ++mi)
    #pragma unroll
    for (int ni = 0; ni < NFR; ++ni)
      acc[mi][ni] = (facc4){0.f, 0.f, 0.f, 0.f};

  const int nk = K >> 5;
  STAGE(0, 0);
  if constexpr (DEPTH == 2) STAGE(1, 1);
  int cur = 0;
  for (int it = 0; it < nk; ++it) {
    if constexpr (DEPTH == 2) {
      if (it + 2 < nk) {
        STAGE((cur + 2) % NBUF, it + 2);
        asm volatile("s_waitcnt vmcnt(%0)" :: "n"(2 * NLOADS) : "memory");
      } else if (it + 1 < nk) {
        asm volatile("s_waitcnt vmcnt(%0)" :: "n"(NLOADS) : "memory");
      } else {
        asm volatile("s_waitcnt vmcnt(0)" ::: "memory");
      }
    } else {
      if (it + 1 < nk) {
        STAGE((cur + 1) % NBUF, it + 1);
        asm volatile("s_waitcnt vmcnt(%0)" :: "n"(NLOADS) : "memory");
      } else {
        asm volatile("s_waitcnt vmcnt(0)" ::: "memory");
      }
    }
    __builtin_amdgcn_sched_barrier(0);
    __builtin_amdgcn_s_barrier();
    __builtin_amdgcn_sched_barrier(0);
    bfrag8 af[MFR], bf[NFR];
    #pragma unroll
    for (int mi = 0; mi < MFR; ++mi)
      af[mi] = *reinterpret_cast<const bfrag8*>(&As[cur][wr*(BM/2) + mi*16 + l16][swzrd]);
    #pragma unroll
    for (int ni = 0; ni < NFR; ++ni)
      bf[ni] = *reinterpret_cast<const bfrag8*>(&Bs[cur][wc*(TN/2) + ni*16 + l16][swzrd]);
    #pragma unroll
    for (int mi = 0; mi < MFR; ++mi)
      #pragma unroll
      for (int ni = 0; ni < NFR; ++ni)
        acc[mi][ni] = MFMA16(af[mi], bf[ni], acc[mi][ni]);
    cur = (cur + 1) % NBUF;
  }

  #pragma unroll
  for (int mi = 0; mi < MFR; ++mi)
    #pragma unroll
    for (int ni = 0; ni < NFR; ++ni) {
      int col = n0 + wc*(TN/2) + ni*16 + l16;
      if (col >= Nreal) continue;
      float bv = bias[col];
      #pragma unroll
      for (int r2 = 0; r2 < 4; ++r2) {
        int row = m0 + wr*(BM/2) + mi*16 + lk*4 + r2;
        float val = acc[mi][ni][r2] + bv;
        if (ACT == 1) {
          float xx = val;
          val = 0.5f * xx * (1.0f + tanhf(0.7978845608028654f * (xx + 0.044715f * xx * xx * xx)));
        }
        size_t idx = (size_t)row * Nreal + col;
        if (OMODE == 0) {
          if constexpr (RES) val += Rf[idx];
          Cf[idx] = val;
        } else {
          Ch[idx] = f2bf(val);
        }
      }
    }
}

// ---------------------------------------------------------------------------
// Attention staging. K/Q: GLDS with XOR-swizzled source seg + matching read.
// ---------------------------------------------------------------------------
__device__ __forceinline__ void stage_glds64_swz(unsigned short (*dst)[64],
    const unsigned short* __restrict__ src, int ld, int t) {
  int w = t >> 6, lane = t & 63;
  int row8 = lane >> 3;
  int seg = (lane & 7) ^ (row8 & 7);
  const unsigned short* s = src + (size_t)(w*16 + row8) * ld + seg * 8;
  GLDS16(s, &dst[w*16][0]);
  GLDS16(s + (size_t)8 * ld, &dst[w*16 + 8][0]);
}

// ---------------------------------------------------------------------------
// Attention, merged sparse+global, bf16 operands, f32 online softmax.
// K dbuf + stage-1-ahead; all metadata preloaded (clean vmcnt queue);
// 2 barriers per kv-block; 8 explicit bodies (static indexing).
// ---------------------------------------------------------------------------
__global__ __launch_bounds__(256) void attn_kernel(
    const unsigned short* __restrict__ qkvh,
    const int* __restrict__ blk_idx, const float* __restrict__ dedup,
    const int* __restrict__ amask,
    unsigned short* __restrict__ ctxh,
    float* __restrict__ go, float* __restrict__ gm, float* __restrict__ gl) {
  __shared__ alignas(16) unsigned short Qs[64][64];
  __shared__ alignas(16) unsigned short KV2[2][64][64];
  __shared__ alignas(16) unsigned short Vs[64][66];
  __shared__ alignas(16) unsigned short Pt[64][68];
  int h = blockIdx.y;
  int bx = (int)blockIdx.x;
  const bool is_glob = (bx >= 30);
  int g = is_glob ? ((bx - 30) >> 2) : 0;
  int part = is_glob ? ((bx - 30) & 3) : 0;
  int qi = is_glob ? (g ? (NB - 1) : 0) : (bx + 1);
  int t = threadIdx.x, wave = t >> 6, lane = t & 63, l16 = lane & 15, lk = lane >> 4;
  const int swq0 = ((lk ^ (l16 & 7))) * 8;
  const int swq1 = (((4 + lk) ^ (l16 & 7))) * 8;
  const int vrow = t >> 2, vcolb = (t & 3) * 16;

  int barr[8];
  float addm[8][4];
  #pragma unroll
  for (int kb = 0; kb < 8; ++kb)
    barr[kb] = is_glob ? (part*8 + kb) : blk_idx[qi*NKB + kb];
  #pragma unroll
  for (int kb = 0; kb < 8; ++kb) {
    float dd = is_glob ? 1.0f : dedup[qi*NKB + kb];
    #pragma unroll
    for (int ni = 0; ni < 4; ++ni) {
      float mk = (float)amask[barr[kb]*64 + ni*16 + l16] * dd;
      addm[kb][ni] = (1.0f - mk) * (-1.0e9f);
    }
  }

  stage_glds64_swz(Qs, qkvh + (size_t)(qi*64)*QKVN + h*64, QKVN, t);
  __syncthreads();
  const bfrag8 q0 = *reinterpret_cast<const bfrag8*>(&Qs[wave*16 + l16][swq0]);
  const bfrag8 q1 = *reinterpret_cast<const bfrag8*>(&Qs[wave*16 + l16][swq1]);

  float mrow[4] = {-3.0e38f, -3.0e38f, -3.0e38f, -3.0e38f};
  float lrow[4] = {0.f, 0.f, 0.f, 0.f};
  facc4 o[4];
  #pragma unroll
  for (int ni = 0; ni < 4; ++ni) o[ni] = (facc4){0.f, 0.f, 0.f, 0.f};

  stage_glds64_swz(KV2[0], qkvh + (size_t)(barr[0]*64)*QKVN + DMODEL + h*64, QKVN, t);
  __builtin_amdgcn_sched_barrier(0);
  us8 vA0, vA1, vB0, vB1;
  {
    const unsigned short* vs0 = qkvh + (size_t)(barr[0]*64 + vrow)*QKVN + 2*DMODEL + h*64 + vcolb;
    vA0 = *reinterpret_cast<const us8*>(vs0);
    vA1 = *reinterpret_cast<const us8*>(vs0 + 8);
  }

  auto body = [&](int kb, const us8& vc0, const us8& vc1, us8& vn0, us8& vn1) {
    if (kb + 1 < 8) {
      int bn = barr[kb + 1];
      stage_glds64_swz(KV2[(kb + 1) & 1], qkvh + (size_t)(bn*64)*QKVN + DMODEL + h*64, QKVN, t);
      __builtin_amdgcn_sched_barrier(0);
      const unsigned short* vsn = qkvh + (size_t)(bn*64 + vrow)*QKVN + 2*DMODEL + h*64 + vcolb;
      vn0 = *reinterpret_cast<const us8*>(vsn);
      vn1 = *reinterpret_cast<const us8*>(vsn + 8);
      asm volatile("s_waitcnt vmcnt(4)" ::: "memory");
    } else {
      asm volatile("s_waitcnt vmcnt(0)" ::: "memory");
    }
    __builtin_amdgcn_sched_barrier(0);
    __builtin_amdgcn_s_barrier();
    __builtin_amdgcn_sched_barrier(0);
    float s[4][4];
    #pragma unroll
    for (int ni = 0; ni < 4; ++ni) {
      bfrag8 k0 = *reinterpret_cast<const bfrag8*>(&KV2[kb & 1][ni*16 + l16][swq0]);
      bfrag8 k1 = *reinterpret_cast<const bfrag8*>(&KV2[kb & 1][ni*16 + l16][swq1]);
      facc4 sa = (facc4){0.f, 0.f, 0.f, 0.f};
      sa = MFMA16(q0, k0, sa);
      sa = MFMA16(q1, k1, sa);
      #pragma unroll
      for (int r = 0; r < 4; ++r) s[ni][r] = sa[r] * 0.125f + addm[kb][ni];
    }
    float pexp[4][4];
    #pragma unroll
    for (int r = 0; r < 4; ++r) {
      float tm = fmaxf(fmaxf(s[0][r], s[1][r]), fmaxf(s[2][r], s[3][r]));
      tm = fmaxf(tm, __shfl_xor(tm, 1));
      tm = fmaxf(tm, __shfl_xor(tm, 2));
      tm = fmaxf(tm, __shfl_xor(tm, 4));
      tm = fmaxf(tm, __shfl_xor(tm, 8));
      float mn = fmaxf(mrow[r], tm);
      float f = expf(mrow[r] - mn);
      #pragma unroll
      for (int ni = 0; ni < 4; ++ni) o[ni][r] *= f;
      float ps = 0.0f;
      #pragma unroll
      for (int ni = 0; ni < 4; ++ni) { pexp[ni][r] = expf(s[ni][r] - mn); ps += pexp[ni][r]; }
      ps += __shfl_xor(ps, 1);
      ps += __shfl_xor(ps, 2);
      ps += __shfl_xor(ps, 4);
      ps += __shfl_xor(ps, 8);
      lrow[r] = lrow[r] * f + ps;
      mrow[r] = mn;
    }
    #pragma unroll
    for (int ni = 0; ni < 4; ++ni)
      #pragma unroll
      for (int r = 0; r < 4; ++r)
        Pt[wave*16 + lk*4 + r][ni*16 + l16] = f2bf(pexp[ni][r]);
    #pragma unroll
    for (int j = 0; j < 8; ++j) {
      Vs[vcolb + j][vrow] = vc0[j];
      Vs[vcolb + 8 + j][vrow] = vc1[j];
    }
    asm volatile("s_waitcnt lgkmcnt(0)" ::: "memory");
    __builtin_amdgcn_sched_barrier(0);
    __builtin_amdgcn_s_barrier();
    __builtin_amdgcn_sched_barrier(0);
    #pragma unroll
    for (int kc = 0; kc < 2; ++kc) {
      bfrag8 ph = *reinterpret_cast<const bfrag8*>(&Pt[wave*16 + l16][kc*32 + lk*8]);
      #pragma unroll
      for (int ni = 0; ni < 4; ++ni) {
        bfrag8 vh = *reinterpret_cast<const bfrag8*>(&Vs[ni*16 + l16][kc*32 + lk*8]);
        o[ni] = MFMA16(ph, vh, o[ni]);
      }
    }
  };

  body(0, vA0, vA1, vB0, vB1);
  body(1, vB0, vB1, vA0, vA1);
  body(2, vA0, vA1, vB0, vB1);
  body(3, vB0, vB1, vA0, vA1);
  body(4, vA0, vA1, vB0, vB1);
  body(5, vB0, vB1, vA0, vA1);
  body(6, vA0, vA1, vB0, vB1);
  body(7, vB0, vB1, vA0, vA1);

  if (!is_glob) {
    float invl[4];
    #pragma unroll
    for (int r = 0; r < 4; ++r) invl[r] = 1.0f / lrow[r];
    #pragma unroll
    for (int ni = 0; ni < 4; ++ni)
      #pragma unroll
      for (int r = 0; r < 4; ++r) {
        int row = qi*64 + wave*16 + lk*4 + r;
        int col = h*64 + ni*16 + l16;
        ctxh[(size_t)row*DMODEL + col] = f2bf(o[ni][r] * invl[r]);
      }
  } else {
    int pidx = (g * NHEAD + h) * 4 + part;
    float* gob = go + (size_t)pidx * 64 * 64;
    #pragma unroll
    for (int ni = 0; ni < 4; ++ni)
      #pragma unroll
      for (int r = 0; r < 4; ++r)
        gob[(wave*16 + lk*4 + r) * 64 + ni*16 + l16] = o[ni][r];
    if (l16 == 0) {
      #pragma unroll
      for (int r = 0; r < 4; ++r) {
        int row = wave*16 + lk*4 + r;
        gm[pidx*64 + row] = mrow[r];
        gl[pidx*64 + row] = lrow[r];
      }
    }
  }
}

__global__ __launch_bounds__(256) void gattn_comb_kernel(
    const float* __restrict__ go, const float* __restrict__ gm,
    const float* __restrict__ gl, unsigned short* __restrict__ ctxh) {
  int g = blockIdx.x, h = blockIdx.y;
  int t = threadIdx.x;
  int row = t >> 2, cseg = (t & 3) * 16;
  int base = (g * NHEAD + h) * 4;
  float m = -3.0e38f;
  for (int p = 0; p < 4; ++p) m = fmaxf(m, gm[(base + p)*64 + row]);
  float w[4]; float l = 0.0f;
  for (int p = 0; p < 4; ++p) {
    w[p] = expf(gm[(base + p)*64 + row] - m);
    l += gl[(base + p)*64 + row] * w[p];
  }
  float inv = 1.0f / l;
  int qrow = (g ? (NB - 1) * 64 : 0) + row;
  for (int c = 0; c < 16; ++c) {
    float acc = 0.0f;
    for (int p = 0; p < 4; ++p)
      acc += go[((size_t)(base + p)*64 + row)*64 + cseg + c] * w[p];
    ctxh[(size_t)qrow*DMODEL + h*64 + cseg + c] = f2bf(acc * inv);
  }
}

// ---------------------------------------------------------------------------
// Launch
// ---------------------------------------------------------------------------
extern "C" void kernel_launch(void* const* d_in, const int* in_sizes, int n_in,
                              void* d_out, int out_size, void* d_ws, size_t ws_size,
                              hipStream_t stream) {
  const int*   input_ids  = (const int*)d_in[0];
  const int*   attn_mask  = (const int*)d_in[1];
  const int*   token_type = (const int*)d_in[2];
  const float* word_emb   = (const float*)d_in[3];
  const float* pos_emb    = (const float*)d_in[4];
  const float* type_emb   = (const float*)d_in[5];
  const float* emb_ln_s   = (const float*)d_in[6];
  const float* emb_ln_b   = (const float*)d_in[7];
  const float* Wq = (const float*)d_in[8];
  const float* Wk = (const float*)d_in[9];
  const float* Wv = (const float*)d_in[10];
  const float* bq = (const float*)d_in[11];
  const float* bk = (const float*)d_in[12];
  const float* bv = (const float*)d_in[13];
  const float* Wo = (const float*)d_in[14];
  const float* bo = (const float*)d_in[15];
  const float* ln1_s = (const float*)d_in[16];
  const float* ln1_b = (const float*)d_in[17];
  const float* W1 = (const float*)d_in[18];
  const float* b1 = (const float*)d_in[19];
  const float* W2 = (const float*)d_in[20];
  const float* b2 = (const float*)d_in[21];
  const float* ln2_s = (const float*)d_in[22];
  const float* ln2_b = (const float*)d_in[23];
  const float* fc_w = (const float*)d_in[24];
  const float* fc_b = (const float*)d_in[25];
  float* out = (float*)d_out;

  unsigned char* base = (unsigned char*)d_ws;
  size_t off = 0;
  auto carve = [&](size_t bytes) -> void* {
    void* p = base + off;
    off = (off + bytes + 255) & ~(size_t)255;
    return p;
  };
  int*   blk_i = (int*)carve(256 * 4);
  float* dedup = (float*)carve(256 * 4);
  float* bqkv  = (float*)carve((size_t)NLAYER * QKVN * 4);
  float* x     = (float*)carve((size_t)S_LEN * DMODEL * 4);
  float* tmp   = (float*)carve((size_t)S_LEN * DMODEL * 4);
  unsigned short* xh   = (unsigned short*)carve((size_t)S_LEN * DMODEL * 2);
  unsigned short* qkvh = (unsigned short*)carve((size_t)S_LEN * QKVN * 2);
  unsigned short* ctxh = (unsigned short*)carve((size_t)S_LEN * DMODEL * 2);
  unsigned short* hbh  = (unsigned short*)carve((size_t)S_LEN * FFDIM * 2);
  float* go    = (float*)carve((size_t)2 * NHEAD * 4 * 64 * 64 * 4);
  float* gm    = (float*)carve((size_t)2 * NHEAD * 4 * 64 * 4);
  float* gl    = (float*)carve((size_t)2 * NHEAD * 4 * 64 * 4);
  unsigned short* qkvT = (unsigned short*)carve((size_t)NLAYER * QKVN * DMODEL * 2);
  unsigned short* woT  = (unsigned short*)carve((size_t)NLAYER * DMODEL * DMODEL * 2);
  unsigned short* w1T  = (unsigned short*)carve((size_t)NLAYER * FFDIM * DMODEL * 2);
  unsigned short* w2T  = (unsigned short*)carve((size_t)NLAYER * DMODEL * FFDIM * 2);
  unsigned short* fcT  = (unsigned short*)carve((size_t)VPAD * DMODEL * 2);

  blockmap_kernel<<<1, 1, 0, stream>>>(blk_i, dedup);

  const size_t DD = (size_t)DMODEL * DMODEL;
  dim3 g768(12, 12, NLAYER);
  tconv_kernel<<<g768, 256, 0, stream>>>(Wq, qkvT + 0,            DMODEL, DMODEL, DD, (size_t)QKVN * DMODEL);
  tconv_kernel<<<g768, 256, 0, stream>>>(Wk, qkvT + 768 * DMODEL, DMODEL, DMODEL, DD, (size_t)QKVN * DMODEL);
  tconv_kernel<<<g768, 256, 0, stream>>>(Wv, qkvT + 1536 * DMODEL,DMODEL, DMODEL, DD, (size_t)QKVN * DMODEL);
  tconv_kernel<<<g768, 256, 0, stream>>>(Wo, woT, DMODEL, DMODEL, DD, DD);
  tconv_kernel<<<dim3(48, 12, NLAYER), 256, 0, stream>>>(W1, w1T, DMODEL, FFDIM, (size_t)DMODEL * FFDIM, (size_t)FFDIM * DMODEL);
  tconv_kernel<<<dim3(12, 48, NLAYER), 256, 0, stream>>>(W2, w2T, FFDIM, DMODEL, (size_t)FFDIM * DMODEL, (size_t)DMODEL * FFDIM);
  tconv_kernel<<<dim3(VPAD / 64, 12, 1), 256, 0, stream>>>(fc_w, fcT, DMODEL, VOCAB, 0, 0);
  bias_cat_kernel<<<NLAYER, 256, 0, stream>>>(bq, bk, bv, bqkv);

  embed_ln_kernel<<<S_LEN, 256, 0, stream>>>(input_ids, token_type, word_emb, pos_emb,
                                             type_emb, emb_ln_s, emb_ln_b, x, xh);

  for (int l = 0; l < NLAYER; ++l) {
    gemm14_kernel<64, 4, 256, 2, 0, 0><<<dim3(32, QKVN/256), 256, 0, stream>>>(
        xh, qkvT + (size_t)l * QKVN * DMODEL, bqkv + (size_t)l * QKVN, nullptr,
        nullptr, qkvh, DMODEL, QKVN);

    attn_kernel<<<dim3(38, NHEAD), 256, 0, stream>>>(
        qkvh, blk_i, dedup, attn_mask, ctxh, go, gm, gl);
    gattn_comb_kernel<<<dim3(2, NHEAD), 256, 0, stream>>>(go, gm, gl, ctxh);

    gemm14_kernel<64, 4, 64, 0, 0, 1><<<dim3(32, DMODEL/64), 256, 0, stream>>>(
        ctxh, woT + (size_t)l * DD, bo + (size_t)l * DMODEL, x,
        tmp, nullptr, DMODEL, DMODEL);
    resln_kernel<<<S_LEN, 256, 0, stream>>>(x, tmp, ln1_s + l*DMODEL, ln1_b + l*DMODEL, xh);

    gemm14_kernel<64, 4, 256, 2, 1, 0><<<dim3(32, FFDIM/256), 256, 0, stream>>>(
        xh, w1T + (size_t)l * FFDIM * DMODEL, b1 + (size_t)l * FFDIM, nullptr,
        nullptr, hbh, DMODEL, FFDIM);
    gemm14_kernel<64, 4, 64, 0, 0, 1><<<dim3(32, DMODEL/64), 256, 0, stream>>>(
        hbh, w2T + (size_t)l * DMODEL * FFDIM, b2 + (size_t)l * DMODEL, x,
        tmp, nullptr, FFDIM, DMODEL);
    resln_kernel<<<S_LEN, 256, 0, stream>>>(x, tmp, ln2_s + l*DMODEL, ln2_b + l*DMODEL, xh);
  }

  gemm14_kernel<128, 3, 128, 0, 0, 0><<<dim3(16, VPAD/128), 256, 0, stream>>>(
      xh, fcT, fc_b, nullptr, out, nullptr, DMODEL, VOCAB);
}

// Round 21
// 2395.109 us; speedup vs baseline: 1.0375x; 1.0375x over previous
//
#include <hip/hip_runtime.h>
#include <hip/hip_bf16.h>

// ---------------------------------------------------------------------------
// BigBird forward. bf16 A/B GEMMs (r19-best tiles: BM=64/TN=128 QKV+FF1,
// BM=64/TN=64 Wo+FF2, BM=128/NBUF=3 vocab), residual-add fused into Wo/FF2
// epilogue. ONE barrier/iter, m-fastest + bijective XCD swizzle. Attention:
// K dbuf + stage-1-ahead counted vmcnt, 2 barriers per kv-block.
// ---------------------------------------------------------------------------

#define S_LEN 2048
#define DMODEL 768
#define FFDIM 3072
#define VOCAB 50358
#define VPAD  50432
#define NLAYER 12
#define NHEAD 12
#define NB 32
#define NKB 8
#define QKVN 2304

typedef __attribute__((ext_vector_type(8))) short bfrag8;
typedef __attribute__((ext_vector_type(8))) unsigned short us8;
typedef __attribute__((ext_vector_type(4))) float facc4;

__device__ __forceinline__ unsigned short f2bf(float f) {
  unsigned int u = __builtin_bit_cast(unsigned int, f);
  u += 0x7fffu + ((u >> 16) & 1u);
  return (unsigned short)(u >> 16);
}
__device__ __forceinline__ float bf2f(unsigned short h) {
  unsigned int u = ((unsigned int)h) << 16;
  return __builtin_bit_cast(float, u);
}

#define MFMA16(a, b, c) __builtin_amdgcn_mfma_f32_16x16x32_bf16((a), (b), (c), 0, 0, 0)
#define GLDS16(g, l) __builtin_amdgcn_global_load_lds( \
    (const __attribute__((address_space(1))) void*)(g), \
    (__attribute__((address_space(3))) void*)(l), 16, 0, 0)

// ---------------------------------------------------------------------------
// numpy RNG replication (validated: passes)
// ---------------------------------------------------------------------------
struct Pcg {
  unsigned long long hi, lo, inc_hi, inc_lo;
  int has32; unsigned int buf32;
};

__device__ __forceinline__ void pcg_step(Pcg& p) {
  const unsigned long long MH = 0x2360ed051fc65da4ull;
  const unsigned long long ML = 0x4385df649fccf645ull;
  unsigned long long rl = p.lo * ML;
  unsigned long long rh = __umul64hi(p.lo, ML) + p.lo * MH + p.hi * ML;
  unsigned long long nl = rl + p.inc_lo;
  unsigned long long nh = rh + p.inc_hi + (nl < rl ? 1ull : 0ull);
  p.lo = nl; p.hi = nh;
}
__device__ __forceinline__ unsigned long long pcg_next64(Pcg& p) {
  pcg_step(p);
  unsigned int rot = (unsigned int)(p.hi >> 58);
  unsigned long long x = p.hi ^ p.lo;
  return (x >> rot) | (x << ((64u - rot) & 63u));
}
__device__ __forceinline__ unsigned int pcg_next32(Pcg& p) {
  if (p.has32) { p.has32 = 0; return p.buf32; }
  unsigned long long n = pcg_next64(p);
  p.has32 = 1; p.buf32 = (unsigned int)(n >> 32);
  return (unsigned int)n;
}
__device__ __forceinline__ unsigned int lemire32(Pcg& p, unsigned int rng) {
  unsigned int rng_excl = rng + 1u;
  unsigned long long m = (unsigned long long)pcg_next32(p) * (unsigned long long)rng_excl;
  unsigned int leftover = (unsigned int)m;
  if (leftover < rng_excl) {
    unsigned int threshold = (0xffffffffu - rng) % rng_excl;
    while (leftover < threshold) {
      m = (unsigned long long)pcg_next32(p) * (unsigned long long)rng_excl;
      leftover = (unsigned int)m;
    }
  }
  return (unsigned int)(m >> 32);
}

__global__ void blockmap_kernel(int* __restrict__ blk_idx, float* __restrict__ dedup) {
  if (threadIdx.x != 0 || blockIdx.x != 0) return;
  unsigned int pool[4];
  unsigned int hc = 0x43b0d7e5u;
  auto ss_hash = [&hc](unsigned int val) {
    val ^= hc; hc *= 0x931e8875u; val *= hc; val ^= val >> 16; return val;
  };
  auto ss_mix = [](unsigned int x, unsigned int y) {
    unsigned int r = 0xca01f9ddu * x - 0x4973f715u * y;
    r ^= r >> 16; return r;
  };
  for (int i = 0; i < 4; ++i) pool[i] = ss_hash(0u);
  for (int s = 0; s < 4; ++s)
    for (int d = 0; d < 4; ++d)
      if (s != d) pool[d] = ss_mix(pool[d], ss_hash(pool[s]));
  unsigned int st32[8];
  unsigned int hb = 0x8b51f9ddu;
  for (int i = 0; i < 8; ++i) {
    unsigned int dv = pool[i & 3];
    dv ^= hb; hb *= 0x58f38dedu; dv *= hb; dv ^= dv >> 16;
    st32[i] = dv;
  }
  unsigned long long sd[4];
  for (int i = 0; i < 4; ++i)
    sd[i] = (unsigned long long)st32[2*i] | ((unsigned long long)st32[2*i+1] << 32);
  Pcg p;
  p.inc_hi = (sd[2] << 1) | (sd[3] >> 63);
  p.inc_lo = (sd[3] << 1) | 1ull;
  p.hi = 0ull; p.lo = 0ull;
  pcg_step(p);
  unsigned long long ol = p.lo;
  p.lo = ol + sd[1];
  p.hi = p.hi + sd[0] + (p.lo < ol ? 1ull : 0ull);
  pcg_step(p);
  p.has32 = 0; p.buf32 = 0;

  for (int i = 0; i < NB; ++i) {
    int lst[8];
    lst[0] = 0; lst[1] = NB - 1;
    lst[2] = (i > 0) ? i - 1 : 0;
    lst[3] = i;
    lst[4] = (i + 1 < NB - 1) ? i + 1 : NB - 1;
    bool excl[NB];
    for (int c = 0; c < NB; ++c) excl[c] = false;
    for (int j = 0; j < 5; ++j) excl[lst[j]] = true;
    int cand[NB], n = 0;
    for (int c = 0; c < NB; ++c) if (!excl[c]) cand[n++] = c;
    long long idx[3];
    unsigned long long hs[4] = {~0ull, ~0ull, ~0ull, ~0ull};
    for (int tI = 0; tI < 3; ++tI) {
      unsigned long long j = (unsigned long long)(n - 3 + tI);
      unsigned long long val = (unsigned long long)lemire32(p, (unsigned int)j);
      unsigned long long loc = val & 3ull;
      while (hs[loc] != ~0ull && hs[loc] != val) loc = (loc + 1ull) & 3ull;
      if (hs[loc] == ~0ull) { hs[loc] = val; idx[tI] = (long long)val; }
      else {
        loc = j & 3ull;
        while (hs[loc] != ~0ull) loc = (loc + 1ull) & 3ull;
        hs[loc] = j; idx[tI] = (long long)j;
      }
    }
    for (int fi = 2; fi >= 1; --fi) {
      int fj = (int)lemire32(p, (unsigned int)fi);
      long long tmpv = idx[fi]; idx[fi] = idx[fj]; idx[fj] = tmpv;
    }
    lst[5] = cand[idx[0]]; lst[6] = cand[idx[1]]; lst[7] = cand[idx[2]];

    unsigned int seen = 0u;
    for (int j = 0; j < 8; ++j) {
      blk_idx[i*8 + j] = lst[j];
      dedup[i*8 + j] = ((seen >> lst[j]) & 1u) ? 0.0f : 1.0f;
      seen |= (1u << lst[j]);
    }
  }
}

// ---------------------------------------------------------------------------
// Weight transpose+convert: src f32 [K][N] -> dst bf16 [Npad][K]
// ---------------------------------------------------------------------------
__global__ __launch_bounds__(256) void tconv_kernel(
    const float* __restrict__ src, unsigned short* __restrict__ dst,
    int K, int N, size_t src_stride, size_t dst_stride) {
  __shared__ float tile[64][65];
  src += (size_t)blockIdx.z * src_stride;
  dst += (size_t)blockIdx.z * dst_stride;
  int n0 = blockIdx.x * 64, k0 = blockIdx.y * 64;
  int t = threadIdx.x;
  int tr = t >> 4, tc = (t & 15) * 4;
  if ((N & 3) == 0 && n0 + 64 <= N) {
    #pragma unroll
    for (int i = 0; i < 4; ++i) {
      int k = k0 + tr + i * 16;
      float4 v = *reinterpret_cast<const float4*>(src + (size_t)k * N + n0 + tc);
      tile[tr + i*16][tc + 0] = v.x; tile[tr + i*16][tc + 1] = v.y;
      tile[tr + i*16][tc + 2] = v.z; tile[tr + i*16][tc + 3] = v.w;
    }
  } else if ((N & 1) == 0 && n0 + 64 <= N) {
    #pragma unroll
    for (int i = 0; i < 4; ++i) {
      int k = k0 + tr + i * 16;
      float2 v0 = *reinterpret_cast<const float2*>(src + (size_t)k * N + n0 + tc);
      float2 v1 = *reinterpret_cast<const float2*>(src + (size_t)k * N + n0 + tc + 2);
      tile[tr + i*16][tc + 0] = v0.x; tile[tr + i*16][tc + 1] = v0.y;
      tile[tr + i*16][tc + 2] = v1.x; tile[tr + i*16][tc + 3] = v1.y;
    }
  } else {
    for (int i = 0; i < 4; ++i) {
      int k = k0 + tr + i * 16;
      #pragma unroll
      for (int q2 = 0; q2 < 4; ++q2) {
        int n = n0 + tc + q2;
        tile[tr + i*16][tc + q2] = (n < N) ? src[(size_t)k * N + n] : 0.0f;
      }
    }
  }
  __syncthreads();
  int wr_ = t >> 2, wc_ = (t & 3) * 16;
  us8 w0, w1;
  #pragma unroll
  for (int j = 0; j < 8; ++j) {
    w0[j] = f2bf(tile[wc_ + j][wr_]);
    w1[j] = f2bf(tile[wc_ + 8 + j][wr_]);
  }
  size_t b = (size_t)(n0 + wr_) * K + k0 + wc_;
  *reinterpret_cast<us8*>(dst + b) = w0;
  *reinterpret_cast<us8*>(dst + b + 8) = w1;
}

__global__ void bias_cat_kernel(const float* __restrict__ bq, const float* __restrict__ bk,
                                const float* __restrict__ bv, float* __restrict__ dst) {
  int l = blockIdx.x;
  for (int i = threadIdx.x; i < QKVN; i += blockDim.x) {
    float v = (i < 768) ? bq[l*768 + i] : (i < 1536) ? bk[l*768 + i - 768] : bv[l*768 + i - 1536];
    dst[l*QKVN + i] = v;
  }
}

// ---------------------------------------------------------------------------
// LayerNorm
// ---------------------------------------------------------------------------
__device__ __forceinline__ float block_sum256(float v, float* red) {
  for (int off = 32; off > 0; off >>= 1) v += __shfl_down(v, off);
  int wv = threadIdx.x >> 6;
  if ((threadIdx.x & 63) == 0) red[wv] = v;
  __syncthreads();
  float r = red[0] + red[1] + red[2] + red[3];
  __syncthreads();
  return r;
}

__global__ void embed_ln_kernel(const int* __restrict__ ids, const int* __restrict__ tts,
                                const float* __restrict__ we, const float* __restrict__ pe,
                                const float* __restrict__ te, const float* __restrict__ lns,
                                const float* __restrict__ lnb, float* __restrict__ x,
                                unsigned short* __restrict__ xh) {
  __shared__ float red[4];
  int row = blockIdx.x, t = threadIdx.x;
  int id = ids[row], ty = tts[row];
  float e[3]; float s = 0.0f;
  for (int j = 0; j < 3; ++j) {
    int d = t + 256*j;
    e[j] = we[(size_t)id*DMODEL + d] + pe[(size_t)row*DMODEL + d] + te[(size_t)ty*DMODEL + d];
    s += e[j];
  }
  float mean = block_sum256(s, red) * (1.0f/768.0f);
  float vs = 0.0f;
  for (int j = 0; j < 3; ++j) { float dd = e[j] - mean; vs += dd*dd; }
  float var = block_sum256(vs, red) * (1.0f/768.0f);
  float inv = rsqrtf(var + 1e-12f);
  for (int j = 0; j < 3; ++j) {
    int d = t + 256*j;
    float val = (e[j] - mean) * inv * lns[d] + lnb[d];
    size_t idx = (size_t)row*DMODEL + d;
    x[idx] = val;
    xh[idx] = f2bf(val);
  }
}

// resln v2: input a already holds residual+output sum (fused in GEMM epilogue)
__global__ void resln_kernel(float* __restrict__ x, const float* __restrict__ a,
                             const float* __restrict__ lns, const float* __restrict__ lnb,
                             unsigned short* __restrict__ xh) {
  __shared__ float red[4];
  int row = blockIdx.x, t = threadIdx.x;
  float e[3]; float s = 0.0f;
  for (int j = 0; j < 3; ++j) {
    int d = t + 256*j;
    e[j] = a[(size_t)row*DMODEL + d];
    s += e[j];
  }
  float mean = block_sum256(s, red) * (1.0f/768.0f);
  float vs = 0.0f;
  for (int j = 0; j < 3; ++j) { float dd = e[j] - mean; vs += dd*dd; }
  float var = block_sum256(vs, red) * (1.0f/768.0f);
  float inv = rsqrtf(var + 1e-12f);
  for (int j = 0; j < 3; ++j) {
    int d = t + 256*j;
    float val = (e[j] - mean) * inv * lns[d] + lnb[d];
    size_t idx = (size_t)row*DMODEL + d;
    x[idx] = val;
    xh[idx] = f2bf(val);
  }
}

// ---------------------------------------------------------------------------
// GEMM v14: bf16 A x bf16 B^T. Templated BM {64,128}, NBUF {3,4},
// TN {64,128}, RES (fuse residual add, OMODE==0 only).
// ONE barrier per k-iter. m-fastest + bijective XCD-chunk swizzle.
// ---------------------------------------------------------------------------
template<int BM, int NBUF, int TN, int OMODE, int ACT, int RES>
__global__ __launch_bounds__(256) void gemm14_kernel(
    const unsigned short* __restrict__ A_g, const unsigned short* __restrict__ Bt,
    const float* __restrict__ bias, const float* __restrict__ Rf,
    float* __restrict__ Cf, unsigned short* __restrict__ Ch,
    int K, int Nreal) {
  __shared__ alignas(16) unsigned short As[NBUF][BM][32];
  __shared__ alignas(16) unsigned short Bs[NBUF][TN][32];
  constexpr int MFR = BM / 32;
  constexpr int NFR = TN / 32;
  constexpr int ACALLS = BM / 64;
  constexpr int BCALLS = TN / 64;
  constexpr int NLOADS = ACALLS + BCALLS;
  constexpr int DEPTH = NBUF - 2;
  int t = threadIdx.x;
  int mb = (int)gridDim.x;
  int nwg = mb * (int)gridDim.y;
  int lin = (int)blockIdx.x + mb * (int)blockIdx.y;
  int cpx = nwg >> 3;
  int nl = (lin & 7) * cpx + (lin >> 3);
  int m0 = (nl % mb) * BM, n0 = (nl / mb) * TN;

  int wave = t >> 6, lane = t & 63, l16 = lane & 15, lk = lane >> 4;
  int wr = wave >> 1, wc = wave & 1;
  int row16 = lane >> 2, seg4 = lane & 3;
  const int srcoff = (seg4 ^ ((row16 >> 1) & 3)) * 8;
  const int swzrd = (lk ^ ((l16 >> 1) & 3)) * 8;

  const unsigned short* ag = A_g + (size_t)(m0 + wave*(BM/4) + row16) * K + srcoff;
  const unsigned short* bg = Bt + (size_t)(n0 + wave*(TN/4) + row16) * K + srcoff;
  const size_t K16 = (size_t)16 * K;

  auto STAGE = [&](int buf, int kit) {
    int k0 = kit << 5;
    #pragma unroll
    for (int j = 0; j < ACALLS; ++j)
      GLDS16(ag + (size_t)j * K16 + k0, &As[buf][wave*(BM/4) + 16*j][0]);
    #pragma unroll
    for (int j = 0; j < BCALLS; ++j)
      GLDS16(bg + (size_t)j * K16 + k0, &Bs[buf][wave*(TN/4) + 16*j][0]);
  };

  facc4 acc[MFR][NFR];
  #pragma unroll
  for (int mi = 0; mi < MFR; ++mi)
    #pragma unroll
    for (int ni = 0; ni < NFR; ++ni)
      acc[mi][ni] = (facc4){0.f, 0.f, 0.f, 0.f};

  const int nk = K >> 5;
  STAGE(0, 0);
  if constexpr (DEPTH == 2) STAGE(1, 1);
  int cur = 0;
  for (int it = 0; it < nk; ++it) {
    if constexpr (DEPTH == 2) {
      if (it + 2 < nk) {
        STAGE((cur + 2) % NBUF, it + 2);
        asm volatile("s_waitcnt vmcnt(%0)" :: "n"(2 * NLOADS) : "memory");
      } else if (it + 1 < nk) {
        asm volatile("s_waitcnt vmcnt(%0)" :: "n"(NLOADS) : "memory");
      } else {
        asm volatile("s_waitcnt vmcnt(0)" ::: "memory");
      }
    } else {
      if (it + 1 < nk) {
        STAGE((cur + 1) % NBUF, it + 1);
        asm volatile("s_waitcnt vmcnt(%0)" :: "n"(NLOADS) : "memory");
      } else {
        asm volatile("s_waitcnt vmcnt(0)" ::: "memory");
      }
    }
    __builtin_amdgcn_sched_barrier(0);
    __builtin_amdgcn_s_barrier();
    __builtin_amdgcn_sched_barrier(0);
    bfrag8 af[MFR], bf[NFR];
    #pragma unroll
    for (int mi = 0; mi < MFR; ++mi)
      af[mi] = *reinterpret_cast<const bfrag8*>(&As[cur][wr*(BM/2) + mi*16 + l16][swzrd]);
    #pragma unroll
    for (int ni = 0; ni < NFR; ++ni)
      bf[ni] = *reinterpret_cast<const bfrag8*>(&Bs[cur][wc*(TN/2) + ni*16 + l16][swzrd]);
    #pragma unroll
    for (int mi = 0; mi < MFR; ++mi)
      #pragma unroll
      for (int ni = 0; ni < NFR; ++ni)
        acc[mi][ni] = MFMA16(af[mi], bf[ni], acc[mi][ni]);
    cur = (cur + 1) % NBUF;
  }

  #pragma unroll
  for (int mi = 0; mi < MFR; ++mi)
    #pragma unroll
    for (int ni = 0; ni < NFR; ++ni) {
      int col = n0 + wc*(TN/2) + ni*16 + l16;
      if (col >= Nreal) continue;
      float bv = bias[col];
      #pragma unroll
      for (int r2 = 0; r2 < 4; ++r2) {
        int row = m0 + wr*(BM/2) + mi*16 + lk*4 + r2;
        float val = acc[mi][ni][r2] + bv;
        if (ACT == 1) {
          float xx = val;
          val = 0.5f * xx * (1.0f + tanhf(0.7978845608028654f * (xx + 0.044715f * xx * xx * xx)));
        }
        size_t idx = (size_t)row * Nreal + col;
        if (OMODE == 0) {
          if constexpr (RES) val += Rf[idx];
          Cf[idx] = val;
        } else {
          Ch[idx] = f2bf(val);
        }
      }
    }
}

// ---------------------------------------------------------------------------
// Attention staging. K/Q: GLDS with XOR-swizzled source seg + matching read.
// ---------------------------------------------------------------------------
__device__ __forceinline__ void stage_glds64_swz(unsigned short (*dst)[64],
    const unsigned short* __restrict__ src, int ld, int t) {
  int w = t >> 6, lane = t & 63;
  int row8 = lane >> 3;
  int seg = (lane & 7) ^ (row8 & 7);
  const unsigned short* s = src + (size_t)(w*16 + row8) * ld + seg * 8;
  GLDS16(s, &dst[w*16][0]);
  GLDS16(s + (size_t)8 * ld, &dst[w*16 + 8][0]);
}

// ---------------------------------------------------------------------------
// Attention, merged sparse+global, bf16 operands, f32 online softmax.
// K dbuf + stage-1-ahead; all metadata preloaded (clean vmcnt queue);
// 2 barriers per kv-block; 8 explicit bodies (static indexing).
// ---------------------------------------------------------------------------
__global__ __launch_bounds__(256) void attn_kernel(
    const unsigned short* __restrict__ qkvh,
    const int* __restrict__ blk_idx, const float* __restrict__ dedup,
    const int* __restrict__ amask,
    unsigned short* __restrict__ ctxh,
    float* __restrict__ go, float* __restrict__ gm, float* __restrict__ gl) {
  __shared__ alignas(16) unsigned short Qs[64][64];
  __shared__ alignas(16) unsigned short KV2[2][64][64];
  __shared__ alignas(16) unsigned short Vs[64][66];
  __shared__ alignas(16) unsigned short Pt[64][68];
  int h = blockIdx.y;
  int bx = (int)blockIdx.x;
  const bool is_glob = (bx >= 30);
  int g = is_glob ? ((bx - 30) >> 2) : 0;
  int part = is_glob ? ((bx - 30) & 3) : 0;
  int qi = is_glob ? (g ? (NB - 1) : 0) : (bx + 1);
  int t = threadIdx.x, wave = t >> 6, lane = t & 63, l16 = lane & 15, lk = lane >> 4;
  const int swq0 = ((lk ^ (l16 & 7))) * 8;
  const int swq1 = (((4 + lk) ^ (l16 & 7))) * 8;
  const int vrow = t >> 2, vcolb = (t & 3) * 16;

  int barr[8];
  float addm[8][4];
  #pragma unroll
  for (int kb = 0; kb < 8; ++kb)
    barr[kb] = is_glob ? (part*8 + kb) : blk_idx[qi*NKB + kb];
  #pragma unroll
  for (int kb = 0; kb < 8; ++kb) {
    float dd = is_glob ? 1.0f : dedup[qi*NKB + kb];
    #pragma unroll
    for (int ni = 0; ni < 4; ++ni) {
      float mk = (float)amask[barr[kb]*64 + ni*16 + l16] * dd;
      addm[kb][ni] = (1.0f - mk) * (-1.0e9f);
    }
  }

  stage_glds64_swz(Qs, qkvh + (size_t)(qi*64)*QKVN + h*64, QKVN, t);
  __syncthreads();
  const bfrag8 q0 = *reinterpret_cast<const bfrag8*>(&Qs[wave*16 + l16][swq0]);
  const bfrag8 q1 = *reinterpret_cast<const bfrag8*>(&Qs[wave*16 + l16][swq1]);

  float mrow[4] = {-3.0e38f, -3.0e38f, -3.0e38f, -3.0e38f};
  float lrow[4] = {0.f, 0.f, 0.f, 0.f};
  facc4 o[4];
  #pragma unroll
  for (int ni = 0; ni < 4; ++ni) o[ni] = (facc4){0.f, 0.f, 0.f, 0.f};

  stage_glds64_swz(KV2[0], qkvh + (size_t)(barr[0]*64)*QKVN + DMODEL + h*64, QKVN, t);
  __builtin_amdgcn_sched_barrier(0);
  us8 vA0, vA1, vB0, vB1;
  {
    const unsigned short* vs0 = qkvh + (size_t)(barr[0]*64 + vrow)*QKVN + 2*DMODEL + h*64 + vcolb;
    vA0 = *reinterpret_cast<const us8*>(vs0);
    vA1 = *reinterpret_cast<const us8*>(vs0 + 8);
  }

  auto body = [&](int kb, const us8& vc0, const us8& vc1, us8& vn0, us8& vn1) {
    if (kb + 1 < 8) {
      int bn = barr[kb + 1];
      stage_glds64_swz(KV2[(kb + 1) & 1], qkvh + (size_t)(bn*64)*QKVN + DMODEL + h*64, QKVN, t);
      __builtin_amdgcn_sched_barrier(0);
      const unsigned short* vsn = qkvh + (size_t)(bn*64 + vrow)*QKVN + 2*DMODEL + h*64 + vcolb;
      vn0 = *reinterpret_cast<const us8*>(vsn);
      vn1 = *reinterpret_cast<const us8*>(vsn + 8);
      asm volatile("s_waitcnt vmcnt(4)" ::: "memory");
    } else {
      asm volatile("s_waitcnt vmcnt(0)" ::: "memory");
    }
    __builtin_amdgcn_sched_barrier(0);
    __builtin_amdgcn_s_barrier();
    __builtin_amdgcn_sched_barrier(0);
    float s[4][4];
    #pragma unroll
    for (int ni = 0; ni < 4; ++ni) {
      bfrag8 k0 = *reinterpret_cast<const bfrag8*>(&KV2[kb & 1][ni*16 + l16][swq0]);
      bfrag8 k1 = *reinterpret_cast<const bfrag8*>(&KV2[kb & 1][ni*16 + l16][swq1]);
      facc4 sa = (facc4){0.f, 0.f, 0.f, 0.f};
      sa = MFMA16(q0, k0, sa);
      sa = MFMA16(q1, k1, sa);
      #pragma unroll
      for (int r = 0; r < 4; ++r) s[ni][r] = sa[r] * 0.125f + addm[kb][ni];
    }
    float pexp[4][4];
    #pragma unroll
    for (int r = 0; r < 4; ++r) {
      float tm = fmaxf(fmaxf(s[0][r], s[1][r]), fmaxf(s[2][r], s[3][r]));
      tm = fmaxf(tm, __shfl_xor(tm, 1));
      tm = fmaxf(tm, __shfl_xor(tm, 2));
      tm = fmaxf(tm, __shfl_xor(tm, 4));
      tm = fmaxf(tm, __shfl_xor(tm, 8));
      float mn = fmaxf(mrow[r], tm);
      float f = expf(mrow[r] - mn);
      #pragma unroll
      for (int ni = 0; ni < 4; ++ni) o[ni][r] *= f;
      float ps = 0.0f;
      #pragma unroll
      for (int ni = 0; ni < 4; ++ni) { pexp[ni][r] = expf(s[ni][r] - mn); ps += pexp[ni][r]; }
      ps += __shfl_xor(ps, 1);
      ps += __shfl_xor(ps, 2);
      ps += __shfl_xor(ps, 4);
      ps += __shfl_xor(ps, 8);
      lrow[r] = lrow[r] * f + ps;
      mrow[r] = mn;
    }
    #pragma unroll
    for (int ni = 0; ni < 4; ++ni)
      #pragma unroll
      for (int r = 0; r < 4; ++r)
        Pt[wave*16 + lk*4 + r][ni*16 + l16] = f2bf(pexp[ni][r]);
    #pragma unroll
    for (int j = 0; j < 8; ++j) {
      Vs[vcolb + j][vrow] = vc0[j];
      Vs[vcolb + 8 + j][vrow] = vc1[j];
    }
    asm volatile("s_waitcnt lgkmcnt(0)" ::: "memory");
    __builtin_amdgcn_sched_barrier(0);
    __builtin_amdgcn_s_barrier();
    __builtin_amdgcn_sched_barrier(0);
    #pragma unroll
    for (int kc = 0; kc < 2; ++kc) {
      bfrag8 ph = *reinterpret_cast<const bfrag8*>(&Pt[wave*16 + l16][kc*32 + lk*8]);
      #pragma unroll
      for (int ni = 0; ni < 4; ++ni) {
        bfrag8 vh = *reinterpret_cast<const bfrag8*>(&Vs[ni*16 + l16][kc*32 + lk*8]);
        o[ni] = MFMA16(ph, vh, o[ni]);
      }
    }
  };

  body(0, vA0, vA1, vB0, vB1);
  body(1, vB0, vB1, vA0, vA1);
  body(2, vA0, vA1, vB0, vB1);
  body(3, vB0, vB1, vA0, vA1);
  body(4, vA0, vA1, vB0, vB1);
  body(5, vB0, vB1, vA0, vA1);
  body(6, vA0, vA1, vB0, vB1);
  body(7, vB0, vB1, vA0, vA1);

  if (!is_glob) {
    float invl[4];
    #pragma unroll
    for (int r = 0; r < 4; ++r) invl[r] = 1.0f / lrow[r];
    #pragma unroll
    for (int ni = 0; ni < 4; ++ni)
      #pragma unroll
      for (int r = 0; r < 4; ++r) {
        int row = qi*64 + wave*16 + lk*4 + r;
        int col = h*64 + ni*16 + l16;
        ctxh[(size_t)row*DMODEL + col] = f2bf(o[ni][r] * invl[r]);
      }
  } else {
    int pidx = (g * NHEAD + h) * 4 + part;
    float* gob = go + (size_t)pidx * 64 * 64;
    #pragma unroll
    for (int ni = 0; ni < 4; ++ni)
      #pragma unroll
      for (int r = 0; r < 4; ++r)
        gob[(wave*16 + lk*4 + r) * 64 + ni*16 + l16] = o[ni][r];
    if (l16 == 0) {
      #pragma unroll
      for (int r = 0; r < 4; ++r) {
        int row = wave*16 + lk*4 + r;
        gm[pidx*64 + row] = mrow[r];
        gl[pidx*64 + row] = lrow[r];
      }
    }
  }
}

__global__ __launch_bounds__(256) void gattn_comb_kernel(
    const float* __restrict__ go, const float* __restrict__ gm,
    const float* __restrict__ gl, unsigned short* __restrict__ ctxh) {
  int g = blockIdx.x, h = blockIdx.y;
  int t = threadIdx.x;
  int row = t >> 2, cseg = (t & 3) * 16;
  int base = (g * NHEAD + h) * 4;
  float m = -3.0e38f;
  for (int p = 0; p < 4; ++p) m = fmaxf(m, gm[(base + p)*64 + row]);
  float w[4]; float l = 0.0f;
  for (int p = 0; p < 4; ++p) {
    w[p] = expf(gm[(base + p)*64 + row] - m);
    l += gl[(base + p)*64 + row] * w[p];
  }
  float inv = 1.0f / l;
  int qrow = (g ? (NB - 1) * 64 : 0) + row;
  for (int c = 0; c < 16; ++c) {
    float acc = 0.0f;
    for (int p = 0; p < 4; ++p)
      acc += go[((size_t)(base + p)*64 + row)*64 + cseg + c] * w[p];
    ctxh[(size_t)qrow*DMODEL + h*64 + cseg + c] = f2bf(acc * inv);
  }
}

// ---------------------------------------------------------------------------
// Launch
// ---------------------------------------------------------------------------
extern "C" void kernel_launch(void* const* d_in, const int* in_sizes, int n_in,
                              void* d_out, int out_size, void* d_ws, size_t ws_size,
                              hipStream_t stream) {
  const int*   input_ids  = (const int*)d_in[0];
  const int*   attn_mask  = (const int*)d_in[1];
  const int*   token_type = (const int*)d_in[2];
  const float* word_emb   = (const float*)d_in[3];
  const float* pos_emb    = (const float*)d_in[4];
  const float* type_emb   = (const float*)d_in[5];
  const float* emb_ln_s   = (const float*)d_in[6];
  const float* emb_ln_b   = (const float*)d_in[7];
  const float* Wq = (const float*)d_in[8];
  const float* Wk = (const float*)d_in[9];
  const float* Wv = (const float*)d_in[10];
  const float* bq = (const float*)d_in[11];
  const float* bk = (const float*)d_in[12];
  const float* bv = (const float*)d_in[13];
  const float* Wo = (const float*)d_in[14];
  const float* bo = (const float*)d_in[15];
  const float* ln1_s = (const float*)d_in[16];
  const float* ln1_b = (const float*)d_in[17];
  const float* W1 = (const float*)d_in[18];
  const float* b1 = (const float*)d_in[19];
  const float* W2 = (const float*)d_in[20];
  const float* b2 = (const float*)d_in[21];
  const float* ln2_s = (const float*)d_in[22];
  const float* ln2_b = (const float*)d_in[23];
  const float* fc_w = (const float*)d_in[24];
  const float* fc_b = (const float*)d_in[25];
  float* out = (float*)d_out;

  unsigned char* base = (unsigned char*)d_ws;
  size_t off = 0;
  auto carve = [&](size_t bytes) -> void* {
    void* p = base + off;
    off = (off + bytes + 255) & ~(size_t)255;
    return p;
  };
  int*   blk_i = (int*)carve(256 * 4);
  float* dedup = (float*)carve(256 * 4);
  float* bqkv  = (float*)carve((size_t)NLAYER * QKVN * 4);
  float* x     = (float*)carve((size_t)S_LEN * DMODEL * 4);
  float* tmp   = (float*)carve((size_t)S_LEN * DMODEL * 4);
  unsigned short* xh   = (unsigned short*)carve((size_t)S_LEN * DMODEL * 2);
  unsigned short* qkvh = (unsigned short*)carve((size_t)S_LEN * QKVN * 2);
  unsigned short* ctxh = (unsigned short*)carve((size_t)S_LEN * DMODEL * 2);
  unsigned short* hbh  = (unsigned short*)carve((size_t)S_LEN * FFDIM * 2);
  float* go    = (float*)carve((size_t)2 * NHEAD * 4 * 64 * 64 * 4);
  float* gm    = (float*)carve((size_t)2 * NHEAD * 4 * 64 * 4);
  float* gl    = (float*)carve((size_t)2 * NHEAD * 4 * 64 * 4);
  unsigned short* qkvT = (unsigned short*)carve((size_t)NLAYER * QKVN * DMODEL * 2);
  unsigned short* woT  = (unsigned short*)carve((size_t)NLAYER * DMODEL * DMODEL * 2);
  unsigned short* w1T  = (unsigned short*)carve((size_t)NLAYER * FFDIM * DMODEL * 2);
  unsigned short* w2T  = (unsigned short*)carve((size_t)NLAYER * DMODEL * FFDIM * 2);
  unsigned short* fcT  = (unsigned short*)carve((size_t)VPAD * DMODEL * 2);

  blockmap_kernel<<<1, 1, 0, stream>>>(blk_i, dedup);

  const size_t DD = (size_t)DMODEL * DMODEL;
  dim3 g768(12, 12, NLAYER);
  tconv_kernel<<<g768, 256, 0, stream>>>(Wq, qkvT + 0,            DMODEL, DMODEL, DD, (size_t)QKVN * DMODEL);
  tconv_kernel<<<g768, 256, 0, stream>>>(Wk, qkvT + 768 * DMODEL, DMODEL, DMODEL, DD, (size_t)QKVN * DMODEL);
  tconv_kernel<<<g768, 256, 0, stream>>>(Wv, qkvT + 1536 * DMODEL,DMODEL, DMODEL, DD, (size_t)QKVN * DMODEL);
  tconv_kernel<<<g768, 256, 0, stream>>>(Wo, woT, DMODEL, DMODEL, DD, DD);
  tconv_kernel<<<dim3(48, 12, NLAYER), 256, 0, stream>>>(W1, w1T, DMODEL, FFDIM, (size_t)DMODEL * FFDIM, (size_t)FFDIM * DMODEL);
  tconv_kernel<<<dim3(12, 48, NLAYER), 256, 0, stream>>>(W2, w2T, FFDIM, DMODEL, (size_t)FFDIM * DMODEL, (size_t)DMODEL * FFDIM);
  tconv_kernel<<<dim3(VPAD / 64, 12, 1), 256, 0, stream>>>(fc_w, fcT, DMODEL, VOCAB, 0, 0);
  bias_cat_kernel<<<NLAYER, 256, 0, stream>>>(bq, bk, bv, bqkv);

  embed_ln_kernel<<<S_LEN, 256, 0, stream>>>(input_ids, token_type, word_emb, pos_emb,
                                             type_emb, emb_ln_s, emb_ln_b, x, xh);

  for (int l = 0; l < NLAYER; ++l) {
    gemm14_kernel<64, 4, 128, 2, 0, 0><<<dim3(32, QKVN/128), 256, 0, stream>>>(
        xh, qkvT + (size_t)l * QKVN * DMODEL, bqkv + (size_t)l * QKVN, nullptr,
        nullptr, qkvh, DMODEL, QKVN);

    attn_kernel<<<dim3(38, NHEAD), 256, 0, stream>>>(
        qkvh, blk_i, dedup, attn_mask, ctxh, go, gm, gl);
    gattn_comb_kernel<<<dim3(2, NHEAD), 256, 0, stream>>>(go, gm, gl, ctxh);

    gemm14_kernel<64, 4, 64, 0, 0, 1><<<dim3(32, DMODEL/64), 256, 0, stream>>>(
        ctxh, woT + (size_t)l * DD, bo + (size_t)l * DMODEL, x,
        tmp, nullptr, DMODEL, DMODEL);
    resln_kernel<<<S_LEN, 256, 0, stream>>>(x, tmp, ln1_s + l*DMODEL, ln1_b + l*DMODEL, xh);

    gemm14_kernel<64, 4, 128, 2, 1, 0><<<dim3(32, FFDIM/128), 256, 0, stream>>>(
        xh, w1T + (size_t)l * FFDIM * DMODEL, b1 + (size_t)l * FFDIM, nullptr,
        nullptr, hbh, DMODEL, FFDIM);
    gemm14_kernel<64, 4, 64, 0, 0, 1><<<dim3(32, DMODEL/64), 256, 0, stream>>>(
        hbh, w2T + (size_t)l * DMODEL * FFDIM, b2 + (size_t)l * DMODEL, x,
        tmp, nullptr, FFDIM, DMODEL);
    resln_kernel<<<S_LEN, 256, 0, stream>>>(x, tmp, ln2_s + l*DMODEL, ln2_b + l*DMODEL, xh);
  }

  gemm14_kernel<128, 3, 128, 0, 0, 0><<<dim3(16, VPAD/128), 256, 0, stream>>>(
      xh, fcT, fc_b, nullptr, out, nullptr, DMODEL, VOCAB);
}

// Round 23
// 2201.454 us; speedup vs baseline: 1.1288x; 1.0880x over previous
//
#include <hip/hip_runtime.h>
#include <hip/hip_bf16.h>

// ---------------------------------------------------------------------------
// BigBird forward. bf16 A/B GEMMs (r19-best tiles), FF2 split-K x2 (partial
// f32 buffers, summed in LN). ONE barrier/iter, m-fastest + bijective XCD
// swizzle. Attention: K dbuf + stage-1-ahead counted vmcnt (r19).
// ---------------------------------------------------------------------------

#define S_LEN 2048
#define DMODEL 768
#define FFDIM 3072
#define VOCAB 50358
#define VPAD  50432
#define NLAYER 12
#define NHEAD 12
#define NB 32
#define NKB 8
#define QKVN 2304

typedef __attribute__((ext_vector_type(8))) short bfrag8;
typedef __attribute__((ext_vector_type(8))) unsigned short us8;
typedef __attribute__((ext_vector_type(4))) float facc4;

__device__ __forceinline__ unsigned short f2bf(float f) {
  unsigned int u = __builtin_bit_cast(unsigned int, f);
  u += 0x7fffu + ((u >> 16) & 1u);
  return (unsigned short)(u >> 16);
}
__device__ __forceinline__ float bf2f(unsigned short h) {
  unsigned int u = ((unsigned int)h) << 16;
  return __builtin_bit_cast(float, u);
}

#define MFMA16(a, b, c) __builtin_amdgcn_mfma_f32_16x16x32_bf16((a), (b), (c), 0, 0, 0)
#define GLDS16(g, l) __builtin_amdgcn_global_load_lds( \
    (const __attribute__((address_space(1))) void*)(g), \
    (__attribute__((address_space(3))) void*)(l), 16, 0, 0)

// ---------------------------------------------------------------------------
// numpy RNG replication (validated: passes)
// ---------------------------------------------------------------------------
struct Pcg {
  unsigned long long hi, lo, inc_hi, inc_lo;
  int has32; unsigned int buf32;
};

__device__ __forceinline__ void pcg_step(Pcg& p) {
  const unsigned long long MH = 0x2360ed051fc65da4ull;
  const unsigned long long ML = 0x4385df649fccf645ull;
  unsigned long long rl = p.lo * ML;
  unsigned long long rh = __umul64hi(p.lo, ML) + p.lo * MH + p.hi * ML;
  unsigned long long nl = rl + p.inc_lo;
  unsigned long long nh = rh + p.inc_hi + (nl < rl ? 1ull : 0ull);
  p.lo = nl; p.hi = nh;
}
__device__ __forceinline__ unsigned long long pcg_next64(Pcg& p) {
  pcg_step(p);
  unsigned int rot = (unsigned int)(p.hi >> 58);
  unsigned long long x = p.hi ^ p.lo;
  return (x >> rot) | (x << ((64u - rot) & 63u));
}
__device__ __forceinline__ unsigned int pcg_next32(Pcg& p) {
  if (p.has32) { p.has32 = 0; return p.buf32; }
  unsigned long long n = pcg_next64(p);
  p.has32 = 1; p.buf32 = (unsigned int)(n >> 32);
  return (unsigned int)n;
}
__device__ __forceinline__ unsigned int lemire32(Pcg& p, unsigned int rng) {
  unsigned int rng_excl = rng + 1u;
  unsigned long long m = (unsigned long long)pcg_next32(p) * (unsigned long long)rng_excl;
  unsigned int leftover = (unsigned int)m;
  if (leftover < rng_excl) {
    unsigned int threshold = (0xffffffffu - rng) % rng_excl;
    while (leftover < threshold) {
      m = (unsigned long long)pcg_next32(p) * (unsigned long long)rng_excl;
      leftover = (unsigned int)m;
    }
  }
  return (unsigned int)(m >> 32);
}

__global__ void blockmap_kernel(int* __restrict__ blk_idx, float* __restrict__ dedup) {
  if (threadIdx.x != 0 || blockIdx.x != 0) return;
  unsigned int pool[4];
  unsigned int hc = 0x43b0d7e5u;
  auto ss_hash = [&hc](unsigned int val) {
    val ^= hc; hc *= 0x931e8875u; val *= hc; val ^= val >> 16; return val;
  };
  auto ss_mix = [](unsigned int x, unsigned int y) {
    unsigned int r = 0xca01f9ddu * x - 0x4973f715u * y;
    r ^= r >> 16; return r;
  };
  for (int i = 0; i < 4; ++i) pool[i] = ss_hash(0u);
  for (int s = 0; s < 4; ++s)
    for (int d = 0; d < 4; ++d)
      if (s != d) pool[d] = ss_mix(pool[d], ss_hash(pool[s]));
  unsigned int st32[8];
  unsigned int hb = 0x8b51f9ddu;
  for (int i = 0; i < 8; ++i) {
    unsigned int dv = pool[i & 3];
    dv ^= hb; hb *= 0x58f38dedu; dv *= hb; dv ^= dv >> 16;
    st32[i] = dv;
  }
  unsigned long long sd[4];
  for (int i = 0; i < 4; ++i)
    sd[i] = (unsigned long long)st32[2*i] | ((unsigned long long)st32[2*i+1] << 32);
  Pcg p;
  p.inc_hi = (sd[2] << 1) | (sd[3] >> 63);
  p.inc_lo = (sd[3] << 1) | 1ull;
  p.hi = 0ull; p.lo = 0ull;
  pcg_step(p);
  unsigned long long ol = p.lo;
  p.lo = ol + sd[1];
  p.hi = p.hi + sd[0] + (p.lo < ol ? 1ull : 0ull);
  pcg_step(p);
  p.has32 = 0; p.buf32 = 0;

  for (int i = 0; i < NB; ++i) {
    int lst[8];
    lst[0] = 0; lst[1] = NB - 1;
    lst[2] = (i > 0) ? i - 1 : 0;
    lst[3] = i;
    lst[4] = (i + 1 < NB - 1) ? i + 1 : NB - 1;
    bool excl[NB];
    for (int c = 0; c < NB; ++c) excl[c] = false;
    for (int j = 0; j < 5; ++j) excl[lst[j]] = true;
    int cand[NB], n = 0;
    for (int c = 0; c < NB; ++c) if (!excl[c]) cand[n++] = c;
    long long idx[3];
    unsigned long long hs[4] = {~0ull, ~0ull, ~0ull, ~0ull};
    for (int tI = 0; tI < 3; ++tI) {
      unsigned long long j = (unsigned long long)(n - 3 + tI);
      unsigned long long val = (unsigned long long)lemire32(p, (unsigned int)j);
      unsigned long long loc = val & 3ull;
      while (hs[loc] != ~0ull && hs[loc] != val) loc = (loc + 1ull) & 3ull;
      if (hs[loc] == ~0ull) { hs[loc] = val; idx[tI] = (long long)val; }
      else {
        loc = j & 3ull;
        while (hs[loc] != ~0ull) loc = (loc + 1ull) & 3ull;
        hs[loc] = j; idx[tI] = (long long)j;
      }
    }
    for (int fi = 2; fi >= 1; --fi) {
      int fj = (int)lemire32(p, (unsigned int)fi);
      long long tmpv = idx[fi]; idx[fi] = idx[fj]; idx[fj] = tmpv;
    }
    lst[5] = cand[idx[0]]; lst[6] = cand[idx[1]]; lst[7] = cand[idx[2]];

    unsigned int seen = 0u;
    for (int j = 0; j < 8; ++j) {
      blk_idx[i*8 + j] = lst[j];
      dedup[i*8 + j] = ((seen >> lst[j]) & 1u) ? 0.0f : 1.0f;
      seen |= (1u << lst[j]);
    }
  }
}

// ---------------------------------------------------------------------------
// Weight transpose+convert: src f32 [K][N] -> dst bf16 [Npad][K]
// ---------------------------------------------------------------------------
__global__ __launch_bounds__(256) void tconv_kernel(
    const float* __restrict__ src, unsigned short* __restrict__ dst,
    int K, int N, size_t src_stride, size_t dst_stride) {
  __shared__ float tile[64][65];
  src += (size_t)blockIdx.z * src_stride;
  dst += (size_t)blockIdx.z * dst_stride;
  int n0 = blockIdx.x * 64, k0 = blockIdx.y * 64;
  int t = threadIdx.x;
  int tr = t >> 4, tc = (t & 15) * 4;
  if ((N & 3) == 0 && n0 + 64 <= N) {
    #pragma unroll
    for (int i = 0; i < 4; ++i) {
      int k = k0 + tr + i * 16;
      float4 v = *reinterpret_cast<const float4*>(src + (size_t)k * N + n0 + tc);
      tile[tr + i*16][tc + 0] = v.x; tile[tr + i*16][tc + 1] = v.y;
      tile[tr + i*16][tc + 2] = v.z; tile[tr + i*16][tc + 3] = v.w;
    }
  } else if ((N & 1) == 0 && n0 + 64 <= N) {
    #pragma unroll
    for (int i = 0; i < 4; ++i) {
      int k = k0 + tr + i * 16;
      float2 v0 = *reinterpret_cast<const float2*>(src + (size_t)k * N + n0 + tc);
      float2 v1 = *reinterpret_cast<const float2*>(src + (size_t)k * N + n0 + tc + 2);
      tile[tr + i*16][tc + 0] = v0.x; tile[tr + i*16][tc + 1] = v0.y;
      tile[tr + i*16][tc + 2] = v1.x; tile[tr + i*16][tc + 3] = v1.y;
    }
  } else {
    for (int i = 0; i < 4; ++i) {
      int k = k0 + tr + i * 16;
      #pragma unroll
      for (int q2 = 0; q2 < 4; ++q2) {
        int n = n0 + tc + q2;
        tile[tr + i*16][tc + q2] = (n < N) ? src[(size_t)k * N + n] : 0.0f;
      }
    }
  }
  __syncthreads();
  int wr_ = t >> 2, wc_ = (t & 3) * 16;
  us8 w0, w1;
  #pragma unroll
  for (int j = 0; j < 8; ++j) {
    w0[j] = f2bf(tile[wc_ + j][wr_]);
    w1[j] = f2bf(tile[wc_ + 8 + j][wr_]);
  }
  size_t b = (size_t)(n0 + wr_) * K + k0 + wc_;
  *reinterpret_cast<us8*>(dst + b) = w0;
  *reinterpret_cast<us8*>(dst + b + 8) = w1;
}

__global__ void bias_cat_kernel(const float* __restrict__ bq, const float* __restrict__ bk,
                                const float* __restrict__ bv, float* __restrict__ dst) {
  int l = blockIdx.x;
  for (int i = threadIdx.x; i < QKVN; i += blockDim.x) {
    float v = (i < 768) ? bq[l*768 + i] : (i < 1536) ? bk[l*768 + i - 768] : bv[l*768 + i - 1536];
    dst[l*QKVN + i] = v;
  }
}

// ---------------------------------------------------------------------------
// LayerNorm
// ---------------------------------------------------------------------------
__device__ __forceinline__ float block_sum256(float v, float* red) {
  for (int off = 32; off > 0; off >>= 1) v += __shfl_down(v, off);
  int wv = threadIdx.x >> 6;
  if ((threadIdx.x & 63) == 0) red[wv] = v;
  __syncthreads();
  float r = red[0] + red[1] + red[2] + red[3];
  __syncthreads();
  return r;
}

__global__ void embed_ln_kernel(const int* __restrict__ ids, const int* __restrict__ tts,
                                const float* __restrict__ we, const float* __restrict__ pe,
                                const float* __restrict__ te, const float* __restrict__ lns,
                                const float* __restrict__ lnb, float* __restrict__ x,
                                unsigned short* __restrict__ xh) {
  __shared__ float red[4];
  int row = blockIdx.x, t = threadIdx.x;
  int id = ids[row], ty = tts[row];
  float e[3]; float s = 0.0f;
  for (int j = 0; j < 3; ++j) {
    int d = t + 256*j;
    e[j] = we[(size_t)id*DMODEL + d] + pe[(size_t)row*DMODEL + d] + te[(size_t)ty*DMODEL + d];
    s += e[j];
  }
  float mean = block_sum256(s, red) * (1.0f/768.0f);
  float vs = 0.0f;
  for (int j = 0; j < 3; ++j) { float dd = e[j] - mean; vs += dd*dd; }
  float var = block_sum256(vs, red) * (1.0f/768.0f);
  float inv = rsqrtf(var + 1e-12f);
  for (int j = 0; j < 3; ++j) {
    int d = t + 256*j;
    float val = (e[j] - mean) * inv * lns[d] + lnb[d];
    size_t idx = (size_t)row*DMODEL + d;
    x[idx] = val;
    xh[idx] = f2bf(val);
  }
}

// resln: e = x + a  (r19 semantics)
__global__ void resln_kernel(float* __restrict__ x, const float* __restrict__ a,
                             const float* __restrict__ lns, const float* __restrict__ lnb,
                             unsigned short* __restrict__ xh) {
  __shared__ float red[4];
  int row = blockIdx.x, t = threadIdx.x;
  float e[3]; float s = 0.0f;
  for (int j = 0; j < 3; ++j) {
    int d = t + 256*j;
    e[j] = x[(size_t)row*DMODEL + d] + a[(size_t)row*DMODEL + d];
    s += e[j];
  }
  float mean = block_sum256(s, red) * (1.0f/768.0f);
  float vs = 0.0f;
  for (int j = 0; j < 3; ++j) { float dd = e[j] - mean; vs += dd*dd; }
  float var = block_sum256(vs, red) * (1.0f/768.0f);
  float inv = rsqrtf(var + 1e-12f);
  for (int j = 0; j < 3; ++j) {
    int d = t + 256*j;
    float val = (e[j] - mean) * inv * lns[d] + lnb[d];
    size_t idx = (size_t)row*DMODEL + d;
    x[idx] = val;
    xh[idx] = f2bf(val);
  }
}

// resln3: e = x + a0 + a1  (FF2 split-K partials)
__global__ void resln3_kernel(float* __restrict__ x, const float* __restrict__ a0,
                              const float* __restrict__ a1,
                              const float* __restrict__ lns, const float* __restrict__ lnb,
                              unsigned short* __restrict__ xh) {
  __shared__ float red[4];
  int row = blockIdx.x, t = threadIdx.x;
  float e[3]; float s = 0.0f;
  for (int j = 0; j < 3; ++j) {
    int d = t + 256*j;
    size_t idx = (size_t)row*DMODEL + d;
    e[j] = x[idx] + a0[idx] + a1[idx];
    s += e[j];
  }
  float mean = block_sum256(s, red) * (1.0f/768.0f);
  float vs = 0.0f;
  for (int j = 0; j < 3; ++j) { float dd = e[j] - mean; vs += dd*dd; }
  float var = block_sum256(vs, red) * (1.0f/768.0f);
  float inv = rsqrtf(var + 1e-12f);
  for (int j = 0; j < 3; ++j) {
    int d = t + 256*j;
    float val = (e[j] - mean) * inv * lns[d] + lnb[d];
    size_t idx = (size_t)row*DMODEL + d;
    x[idx] = val;
    xh[idx] = f2bf(val);
  }
}

// ---------------------------------------------------------------------------
// GEMM v15: bf16 A x bf16 B^T. Templated BM {64,128}, NBUF {3,4}, TN {64,128},
// SPLITK {0,1}. When SPLITK: K = half-K, LDA = full row stride, blockIdx.z
// selects K half; partial written to Cf + z*M*Nreal; bias only on z==0.
// ONE barrier per k-iter. m-fastest + bijective XCD-chunk swizzle.
// ---------------------------------------------------------------------------
template<int BM, int NBUF, int TN, int OMODE, int ACT, int SPLITK>
__global__ __launch_bounds__(256) void gemm15_kernel(
    const unsigned short* __restrict__ A_g, const unsigned short* __restrict__ Bt,
    const float* __restrict__ bias,
    float* __restrict__ Cf, unsigned short* __restrict__ Ch,
    int K, int Nreal, int LDA, int M) {
  __shared__ alignas(16) unsigned short As[NBUF][BM][32];
  __shared__ alignas(16) unsigned short Bs[NBUF][TN][32];
  constexpr int MFR = BM / 32;
  constexpr int NFR = TN / 32;
  constexpr int ACALLS = BM / 64;
  constexpr int BCALLS = TN / 64;
  constexpr int NLOADS = ACALLS + BCALLS;
  constexpr int DEPTH = NBUF - 2;
  int t = threadIdx.x;
  int mb = (int)gridDim.x;
  int nwg = mb * (int)gridDim.y;
  int lin = (int)blockIdx.x + mb * (int)blockIdx.y;
  int cpx = nwg >> 3;
  int nl = (lin & 7) * cpx + (lin >> 3);
  int m0 = (nl % mb) * BM, n0 = (nl / mb) * TN;
  int koff = SPLITK ? (int)blockIdx.z * K : 0;

  int wave = t >> 6, lane = t & 63, l16 = lane & 15, lk = lane >> 4;
  int wr = wave >> 1, wc = wave & 1;
  int row16 = lane >> 2, seg4 = lane & 3;
  const int srcoff = (seg4 ^ ((row16 >> 1) & 3)) * 8;
  const int swzrd = (lk ^ ((l16 >> 1) & 3)) * 8;

  const unsigned short* ag = A_g + (size_t)(m0 + wave*(BM/4) + row16) * LDA + koff + srcoff;
  const unsigned short* bg = Bt + (size_t)(n0 + wave*(TN/4) + row16) * LDA + koff + srcoff;
  const size_t K16 = (size_t)16 * LDA;

  auto STAGE = [&](int buf, int kit) {
    int k0 = kit << 5;
    #pragma unroll
    for (int j = 0; j < ACALLS; ++j)
      GLDS16(ag + (size_t)j * K16 + k0, &As[buf][wave*(BM/4) + 16*j][0]);
    #pragma unroll
    for (int j = 0; j < BCALLS; ++j)
      GLDS16(bg + (size_t)j * K16 + k0, &Bs[buf][wave*(TN/4) + 16*j][0]);
  };

  facc4 acc[MFR][NFR];
  #pragma unroll
  for (int mi = 0; mi < MFR; ++mi)
    #pragma unroll
    for (int ni = 0; ni < NFR; ++ni)
      acc[mi][ni] = (facc4){0.f, 0.f, 0.f, 0.f};

  const int nk = K >> 5;
  STAGE(0, 0);
  if constexpr (DEPTH == 2) STAGE(1, 1);
  int cur = 0;
  for (int it = 0; it < nk; ++it) {
    if constexpr (DEPTH == 2) {
      if (it + 2 < nk) {
        STAGE((cur + 2) % NBUF, it + 2);
        asm volatile("s_waitcnt vmcnt(%0)" :: "n"(2 * NLOADS) : "memory");
      } else if (it + 1 < nk) {
        asm volatile("s_waitcnt vmcnt(%0)" :: "n"(NLOADS) : "memory");
      } else {
        asm volatile("s_waitcnt vmcnt(0)" ::: "memory");
      }
    } else {
      if (it + 1 < nk) {
        STAGE((cur + 1) % NBUF, it + 1);
        asm volatile("s_waitcnt vmcnt(%0)" :: "n"(NLOADS) : "memory");
      } else {
        asm volatile("s_waitcnt vmcnt(0)" ::: "memory");
      }
    }
    __builtin_amdgcn_sched_barrier(0);
    __builtin_amdgcn_s_barrier();
    __builtin_amdgcn_sched_barrier(0);
    bfrag8 af[MFR], bf[NFR];
    #pragma unroll
    for (int mi = 0; mi < MFR; ++mi)
      af[mi] = *reinterpret_cast<const bfrag8*>(&As[cur][wr*(BM/2) + mi*16 + l16][swzrd]);
    #pragma unroll
    for (int ni = 0; ni < NFR; ++ni)
      bf[ni] = *reinterpret_cast<const bfrag8*>(&Bs[cur][wc*(TN/2) + ni*16 + l16][swzrd]);
    #pragma unroll
    for (int mi = 0; mi < MFR; ++mi)
      #pragma unroll
      for (int ni = 0; ni < NFR; ++ni)
        acc[mi][ni] = MFMA16(af[mi], bf[ni], acc[mi][ni]);
    cur = (cur + 1) % NBUF;
  }

  float* cfo = Cf;
  if constexpr (SPLITK) cfo = Cf + (size_t)blockIdx.z * (size_t)M * Nreal;
  bool dobias = !SPLITK || blockIdx.z == 0;

  #pragma unroll
  for (int mi = 0; mi < MFR; ++mi)
    #pragma unroll
    for (int ni = 0; ni < NFR; ++ni) {
      int col = n0 + wc*(TN/2) + ni*16 + l16;
      if (col >= Nreal) continue;
      float bv = dobias ? bias[col] : 0.0f;
      #pragma unroll
      for (int r2 = 0; r2 < 4; ++r2) {
        int row = m0 + wr*(BM/2) + mi*16 + lk*4 + r2;
        float val = acc[mi][ni][r2] + bv;
        if (ACT == 1) {
          float xx = val;
          val = 0.5f * xx * (1.0f + tanhf(0.7978845608028654f * (xx + 0.044715f * xx * xx * xx)));
        }
        size_t idx = (size_t)row * Nreal + col;
        if (OMODE == 0) cfo[idx] = val;
        else Ch[idx] = f2bf(val);
      }
    }
}

// ---------------------------------------------------------------------------
// Attention staging. K/Q: GLDS with XOR-swizzled source seg + matching read.
// ---------------------------------------------------------------------------
__device__ __forceinline__ void stage_glds64_swz(unsigned short (*dst)[64],
    const unsigned short* __restrict__ src, int ld, int t) {
  int w = t >> 6, lane = t & 63;
  int row8 = lane >> 3;
  int seg = (lane & 7) ^ (row8 & 7);
  const unsigned short* s = src + (size_t)(w*16 + row8) * ld + seg * 8;
  GLDS16(s, &dst[w*16][0]);
  GLDS16(s + (size_t)8 * ld, &dst[w*16 + 8][0]);
}

// ---------------------------------------------------------------------------
// Attention, merged sparse+global, bf16 operands, f32 online softmax (r19).
// ---------------------------------------------------------------------------
__global__ __launch_bounds__(256) void attn_kernel(
    const unsigned short* __restrict__ qkvh,
    const int* __restrict__ blk_idx, const float* __restrict__ dedup,
    const int* __restrict__ amask,
    unsigned short* __restrict__ ctxh,
    float* __restrict__ go, float* __restrict__ gm, float* __restrict__ gl) {
  __shared__ alignas(16) unsigned short Qs[64][64];
  __shared__ alignas(16) unsigned short KV2[2][64][64];
  __shared__ alignas(16) unsigned short Vs[64][66];
  __shared__ alignas(16) unsigned short Pt[64][68];
  int h = blockIdx.y;
  int bx = (int)blockIdx.x;
  const bool is_glob = (bx >= 30);
  int g = is_glob ? ((bx - 30) >> 2) : 0;
  int part = is_glob ? ((bx - 30) & 3) : 0;
  int qi = is_glob ? (g ? (NB - 1) : 0) : (bx + 1);
  int t = threadIdx.x, wave = t >> 6, lane = t & 63, l16 = lane & 15, lk = lane >> 4;
  const int swq0 = ((lk ^ (l16 & 7))) * 8;
  const int swq1 = (((4 + lk) ^ (l16 & 7))) * 8;
  const int vrow = t >> 2, vcolb = (t & 3) * 16;

  int barr[8];
  float addm[8][4];
  #pragma unroll
  for (int kb = 0; kb < 8; ++kb)
    barr[kb] = is_glob ? (part*8 + kb) : blk_idx[qi*NKB + kb];
  #pragma unroll
  for (int kb = 0; kb < 8; ++kb) {
    float dd = is_glob ? 1.0f : dedup[qi*NKB + kb];
    #pragma unroll
    for (int ni = 0; ni < 4; ++ni) {
      float mk = (float)amask[barr[kb]*64 + ni*16 + l16] * dd;
      addm[kb][ni] = (1.0f - mk) * (-1.0e9f);
    }
  }

  stage_glds64_swz(Qs, qkvh + (size_t)(qi*64)*QKVN + h*64, QKVN, t);
  __syncthreads();
  const bfrag8 q0 = *reinterpret_cast<const bfrag8*>(&Qs[wave*16 + l16][swq0]);
  const bfrag8 q1 = *reinterpret_cast<const bfrag8*>(&Qs[wave*16 + l16][swq1]);

  float mrow[4] = {-3.0e38f, -3.0e38f, -3.0e38f, -3.0e38f};
  float lrow[4] = {0.f, 0.f, 0.f, 0.f};
  facc4 o[4];
  #pragma unroll
  for (int ni = 0; ni < 4; ++ni) o[ni] = (facc4){0.f, 0.f, 0.f, 0.f};

  stage_glds64_swz(KV2[0], qkvh + (size_t)(barr[0]*64)*QKVN + DMODEL + h*64, QKVN, t);
  __builtin_amdgcn_sched_barrier(0);
  us8 vA0, vA1, vB0, vB1;
  {
    const unsigned short* vs0 = qkvh + (size_t)(barr[0]*64 + vrow)*QKVN + 2*DMODEL + h*64 + vcolb;
    vA0 = *reinterpret_cast<const us8*>(vs0);
    vA1 = *reinterpret_cast<const us8*>(vs0 + 8);
  }

  auto body = [&](int kb, const us8& vc0, const us8& vc1, us8& vn0, us8& vn1) {
    if (kb + 1 < 8) {
      int bn = barr[kb + 1];
      stage_glds64_swz(KV2[(kb + 1) & 1], qkvh + (size_t)(bn*64)*QKVN + DMODEL + h*64, QKVN, t);
      __builtin_amdgcn_sched_barrier(0);
      const unsigned short* vsn = qkvh + (size_t)(bn*64 + vrow)*QKVN + 2*DMODEL + h*64 + vcolb;
      vn0 = *reinterpret_cast<const us8*>(vsn);
      vn1 = *reinterpret_cast<const us8*>(vsn + 8);
      asm volatile("s_waitcnt vmcnt(4)" ::: "memory");
    } else {
      asm volatile("s_waitcnt vmcnt(0)" ::: "memory");
    }
    __builtin_amdgcn_sched_barrier(0);
    __builtin_amdgcn_s_barrier();
    __builtin_amdgcn_sched_barrier(0);
    float s[4][4];
    #pragma unroll
    for (int ni = 0; ni < 4; ++ni) {
      bfrag8 k0 = *reinterpret_cast<const bfrag8*>(&KV2[kb & 1][ni*16 + l16][swq0]);
      bfrag8 k1 = *reinterpret_cast<const bfrag8*>(&KV2[kb & 1][ni*16 + l16][swq1]);
      facc4 sa = (facc4){0.f, 0.f, 0.f, 0.f};
      sa = MFMA16(q0, k0, sa);
      sa = MFMA16(q1, k1, sa);
      #pragma unroll
      for (int r = 0; r < 4; ++r) s[ni][r] = sa[r] * 0.125f + addm[kb][ni];
    }
    float pexp[4][4];
    #pragma unroll
    for (int r = 0; r < 4; ++r) {
      float tm = fmaxf(fmaxf(s[0][r], s[1][r]), fmaxf(s[2][r], s[3][r]));
      tm = fmaxf(tm, __shfl_xor(tm, 1));
      tm = fmaxf(tm, __shfl_xor(tm, 2));
      tm = fmaxf(tm, __shfl_xor(tm, 4));
      tm = fmaxf(tm, __shfl_xor(tm, 8));
      float mn = fmaxf(mrow[r], tm);
      float f = expf(mrow[r] - mn);
      #pragma unroll
      for (int ni = 0; ni < 4; ++ni) o[ni][r] *= f;
      float ps = 0.0f;
      #pragma unroll
      for (int ni = 0; ni < 4; ++ni) { pexp[ni][r] = expf(s[ni][r] - mn); ps += pexp[ni][r]; }
      ps += __shfl_xor(ps, 1);
      ps += __shfl_xor(ps, 2);
      ps += __shfl_xor(ps, 4);
      ps += __shfl_xor(ps, 8);
      lrow[r] = lrow[r] * f + ps;
      mrow[r] = mn;
    }
    #pragma unroll
    for (int ni = 0; ni < 4; ++ni)
      #pragma unroll
      for (int r = 0; r < 4; ++r)
        Pt[wave*16 + lk*4 + r][ni*16 + l16] = f2bf(pexp[ni][r]);
    #pragma unroll
    for (int j = 0; j < 8; ++j) {
      Vs[vcolb + j][vrow] = vc0[j];
      Vs[vcolb + 8 + j][vrow] = vc1[j];
    }
    asm volatile("s_waitcnt lgkmcnt(0)" ::: "memory");
    __builtin_amdgcn_sched_barrier(0);
    __builtin_amdgcn_s_barrier();
    __builtin_amdgcn_sched_barrier(0);
    #pragma unroll
    for (int kc = 0; kc < 2; ++kc) {
      bfrag8 ph = *reinterpret_cast<const bfrag8*>(&Pt[wave*16 + l16][kc*32 + lk*8]);
      #pragma unroll
      for (int ni = 0; ni < 4; ++ni) {
        bfrag8 vh = *reinterpret_cast<const bfrag8*>(&Vs[ni*16 + l16][kc*32 + lk*8]);
        o[ni] = MFMA16(ph, vh, o[ni]);
      }
    }
  };

  body(0, vA0, vA1, vB0, vB1);
  body(1, vB0, vB1, vA0, vA1);
  body(2, vA0, vA1, vB0, vB1);
  body(3, vB0, vB1, vA0, vA1);
  body(4, vA0, vA1, vB0, vB1);
  body(5, vB0, vB1, vA0, vA1);
  body(6, vA0, vA1, vB0, vB1);
  body(7, vB0, vB1, vA0, vA1);

  if (!is_glob) {
    float invl[4];
    #pragma unroll
    for (int r = 0; r < 4; ++r) invl[r] = 1.0f / lrow[r];
    #pragma unroll
    for (int ni = 0; ni < 4; ++ni)
      #pragma unroll
      for (int r = 0; r < 4; ++r) {
        int row = qi*64 + wave*16 + lk*4 + r;
        int col = h*64 + ni*16 + l16;
        ctxh[(size_t)row*DMODEL + col] = f2bf(o[ni][r] * invl[r]);
      }
  } else {
    int pidx = (g * NHEAD + h) * 4 + part;
    float* gob = go + (size_t)pidx * 64 * 64;
    #pragma unroll
    for (int ni = 0; ni < 4; ++ni)
      #pragma unroll
      for (int r = 0; r < 4; ++r)
        gob[(wave*16 + lk*4 + r) * 64 + ni*16 + l16] = o[ni][r];
    if (l16 == 0) {
      #pragma unroll
      for (int r = 0; r < 4; ++r) {
        int row = wave*16 + lk*4 + r;
        gm[pidx*64 + row] = mrow[r];
        gl[pidx*64 + row] = lrow[r];
      }
    }
  }
}

__global__ __launch_bounds__(256) void gattn_comb_kernel(
    const float* __restrict__ go, const float* __restrict__ gm,
    const float* __restrict__ gl, unsigned short* __restrict__ ctxh) {
  int g = blockIdx.x, h = blockIdx.y;
  int t = threadIdx.x;
  int row = t >> 2, cseg = (t & 3) * 16;
  int base = (g * NHEAD + h) * 4;
  float m = -3.0e38f;
  for (int p = 0; p < 4; ++p) m = fmaxf(m, gm[(base + p)*64 + row]);
  float w[4]; float l = 0.0f;
  for (int p = 0; p < 4; ++p) {
    w[p] = expf(gm[(base + p)*64 + row] - m);
    l += gl[(base + p)*64 + row] * w[p];
  }
  float inv = 1.0f / l;
  int qrow = (g ? (NB - 1) * 64 : 0) + row;
  for (int c = 0; c < 16; ++c) {
    float acc = 0.0f;
    for (int p = 0; p < 4; ++p)
      acc += go[((size_t)(base + p)*64 + row)*64 + cseg + c] * w[p];
    ctxh[(size_t)qrow*DMODEL + h*64 + cseg + c] = f2bf(acc * inv);
  }
}

// ---------------------------------------------------------------------------
// Launch
// ---------------------------------------------------------------------------
extern "C" void kernel_launch(void* const* d_in, const int* in_sizes, int n_in,
                              void* d_out, int out_size, void* d_ws, size_t ws_size,
                              hipStream_t stream) {
  const int*   input_ids  = (const int*)d_in[0];
  const int*   attn_mask  = (const int*)d_in[1];
  const int*   token_type = (const int*)d_in[2];
  const float* word_emb   = (const float*)d_in[3];
  const float* pos_emb    = (const float*)d_in[4];
  const float* type_emb   = (const float*)d_in[5];
  const float* emb_ln_s   = (const float*)d_in[6];
  const float* emb_ln_b   = (const float*)d_in[7];
  const float* Wq = (const float*)d_in[8];
  const float* Wk = (const float*)d_in[9];
  const float* Wv = (const float*)d_in[10];
  const float* bq = (const float*)d_in[11];
  const float* bk = (const float*)d_in[12];
  const float* bv = (const float*)d_in[13];
  const float* Wo = (const float*)d_in[14];
  const float* bo = (const float*)d_in[15];
  const float* ln1_s = (const float*)d_in[16];
  const float* ln1_b = (const float*)d_in[17];
  const float* W1 = (const float*)d_in[18];
  const float* b1 = (const float*)d_in[19];
  const float* W2 = (const float*)d_in[20];
  const float* b2 = (const float*)d_in[21];
  const float* ln2_s = (const float*)d_in[22];
  const float* ln2_b = (const float*)d_in[23];
  const float* fc_w = (const float*)d_in[24];
  const float* fc_b = (const float*)d_in[25];
  float* out = (float*)d_out;

  unsigned char* base = (unsigned char*)d_ws;
  size_t off = 0;
  auto carve = [&](size_t bytes) -> void* {
    void* p = base + off;
    off = (off + bytes + 255) & ~(size_t)255;
    return p;
  };
  int*   blk_i = (int*)carve(256 * 4);
  float* dedup = (float*)carve(256 * 4);
  float* bqkv  = (float*)carve((size_t)NLAYER * QKVN * 4);
  float* x     = (float*)carve((size_t)S_LEN * DMODEL * 4);
  float* tmp   = (float*)carve((size_t)2 * S_LEN * DMODEL * 4);   // 2 halves for split-K
  unsigned short* xh   = (unsigned short*)carve((size_t)S_LEN * DMODEL * 2);
  unsigned short* qkvh = (unsigned short*)carve((size_t)S_LEN * QKVN * 2);
  unsigned short* ctxh = (unsigned short*)carve((size_t)S_LEN * DMODEL * 2);
  unsigned short* hbh  = (unsigned short*)carve((size_t)S_LEN * FFDIM * 2);
  float* go    = (float*)carve((size_t)2 * NHEAD * 4 * 64 * 64 * 4);
  float* gm    = (float*)carve((size_t)2 * NHEAD * 4 * 64 * 4);
  float* gl    = (float*)carve((size_t)2 * NHEAD * 4 * 64 * 4);
  unsigned short* qkvT = (unsigned short*)carve((size_t)NLAYER * QKVN * DMODEL * 2);
  unsigned short* woT  = (unsigned short*)carve((size_t)NLAYER * DMODEL * DMODEL * 2);
  unsigned short* w1T  = (unsigned short*)carve((size_t)NLAYER * FFDIM * DMODEL * 2);
  unsigned short* w2T  = (unsigned short*)carve((size_t)NLAYER * DMODEL * FFDIM * 2);
  unsigned short* fcT  = (unsigned short*)carve((size_t)VPAD * DMODEL * 2);

  blockmap_kernel<<<1, 1, 0, stream>>>(blk_i, dedup);

  const size_t DD = (size_t)DMODEL * DMODEL;
  const size_t SD = (size_t)S_LEN * DMODEL;
  dim3 g768(12, 12, NLAYER);
  tconv_kernel<<<g768, 256, 0, stream>>>(Wq, qkvT + 0,            DMODEL, DMODEL, DD, (size_t)QKVN * DMODEL);
  tconv_kernel<<<g768, 256, 0, stream>>>(Wk, qkvT + 768 * DMODEL, DMODEL, DMODEL, DD, (size_t)QKVN * DMODEL);
  tconv_kernel<<<g768, 256, 0, stream>>>(Wv, qkvT + 1536 * DMODEL,DMODEL, DMODEL, DD, (size_t)QKVN * DMODEL);
  tconv_kernel<<<g768, 256, 0, stream>>>(Wo, woT, DMODEL, DMODEL, DD, DD);
  tconv_kernel<<<dim3(48, 12, NLAYER), 256, 0, stream>>>(W1, w1T, DMODEL, FFDIM, (size_t)DMODEL * FFDIM, (size_t)FFDIM * DMODEL);
  tconv_kernel<<<dim3(12, 48, NLAYER), 256, 0, stream>>>(W2, w2T, FFDIM, DMODEL, (size_t)FFDIM * DMODEL, (size_t)DMODEL * FFDIM);
  tconv_kernel<<<dim3(VPAD / 64, 12, 1), 256, 0, stream>>>(fc_w, fcT, DMODEL, VOCAB, 0, 0);
  bias_cat_kernel<<<NLAYER, 256, 0, stream>>>(bq, bk, bv, bqkv);

  embed_ln_kernel<<<S_LEN, 256, 0, stream>>>(input_ids, token_type, word_emb, pos_emb,
                                             type_emb, emb_ln_s, emb_ln_b, x, xh);

  for (int l = 0; l < NLAYER; ++l) {
    gemm15_kernel<64, 4, 128, 2, 0, 0><<<dim3(32, QKVN/128), 256, 0, stream>>>(
        xh, qkvT + (size_t)l * QKVN * DMODEL, bqkv + (size_t)l * QKVN,
        nullptr, qkvh, DMODEL, QKVN, DMODEL, S_LEN);

    attn_kernel<<<dim3(38, NHEAD), 256, 0, stream>>>(
        qkvh, blk_i, dedup, attn_mask, ctxh, go, gm, gl);
    gattn_comb_kernel<<<dim3(2, NHEAD), 256, 0, stream>>>(go, gm, gl, ctxh);

    gemm15_kernel<64, 4, 64, 0, 0, 0><<<dim3(32, DMODEL/64), 256, 0, stream>>>(
        ctxh, woT + (size_t)l * DD, bo + (size_t)l * DMODEL,
        tmp, nullptr, DMODEL, DMODEL, DMODEL, S_LEN);
    resln_kernel<<<S_LEN, 256, 0, stream>>>(x, tmp, ln1_s + l*DMODEL, ln1_b + l*DMODEL, xh);

    gemm15_kernel<64, 4, 128, 2, 1, 0><<<dim3(32, FFDIM/128), 256, 0, stream>>>(
        xh, w1T + (size_t)l * FFDIM * DMODEL, b1 + (size_t)l * FFDIM,
        nullptr, hbh, DMODEL, FFDIM, DMODEL, S_LEN);
    // FF2: split-K x2 -> partials tmp[0..SD), tmp[SD..2SD)
    gemm15_kernel<64, 4, 64, 0, 0, 1><<<dim3(32, DMODEL/64, 2), 256, 0, stream>>>(
        hbh, w2T + (size_t)l * DMODEL * FFDIM, b2 + (size_t)l * DMODEL,
        tmp, nullptr, FFDIM/2, DMODEL, FFDIM, S_LEN);
    resln3_kernel<<<S_LEN, 256, 0, stream>>>(x, tmp, tmp + SD,
                                             ln2_s + l*DMODEL, ln2_b + l*DMODEL, xh);
  }

  gemm15_kernel<128, 3, 128, 0, 0, 0><<<dim3(16, VPAD/128), 256, 0, stream>>>(
      xh, fcT, fc_b, out, nullptr, DMODEL, VOCAB, DMODEL, S_LEN);
}

// Round 24
// 2185.630 us; speedup vs baseline: 1.1369x; 1.0072x over previous
//
#include <hip/hip_runtime.h>
#include <hip/hip_bf16.h>

// ---------------------------------------------------------------------------
// BigBird forward. bf16 A/B GEMMs (r19-best tiles), Wo+FF2 split-K x2
// (partial f32 buffers, summed in LN). ONE barrier/iter, m-fastest +
// bijective XCD swizzle. Attention: K dbuf + stage-1-ahead counted vmcnt.
// ---------------------------------------------------------------------------

#define S_LEN 2048
#define DMODEL 768
#define FFDIM 3072
#define VOCAB 50358
#define VPAD  50432
#define NLAYER 12
#define NHEAD 12
#define NB 32
#define NKB 8
#define QKVN 2304

typedef __attribute__((ext_vector_type(8))) short bfrag8;
typedef __attribute__((ext_vector_type(8))) unsigned short us8;
typedef __attribute__((ext_vector_type(4))) float facc4;

__device__ __forceinline__ unsigned short f2bf(float f) {
  unsigned int u = __builtin_bit_cast(unsigned int, f);
  u += 0x7fffu + ((u >> 16) & 1u);
  return (unsigned short)(u >> 16);
}
__device__ __forceinline__ float bf2f(unsigned short h) {
  unsigned int u = ((unsigned int)h) << 16;
  return __builtin_bit_cast(float, u);
}

#define MFMA16(a, b, c) __builtin_amdgcn_mfma_f32_16x16x32_bf16((a), (b), (c), 0, 0, 0)
#define GLDS16(g, l) __builtin_amdgcn_global_load_lds( \
    (const __attribute__((address_space(1))) void*)(g), \
    (__attribute__((address_space(3))) void*)(l), 16, 0, 0)

// ---------------------------------------------------------------------------
// numpy RNG replication (validated: passes)
// ---------------------------------------------------------------------------
struct Pcg {
  unsigned long long hi, lo, inc_hi, inc_lo;
  int has32; unsigned int buf32;
};

__device__ __forceinline__ void pcg_step(Pcg& p) {
  const unsigned long long MH = 0x2360ed051fc65da4ull;
  const unsigned long long ML = 0x4385df649fccf645ull;
  unsigned long long rl = p.lo * ML;
  unsigned long long rh = __umul64hi(p.lo, ML) + p.lo * MH + p.hi * ML;
  unsigned long long nl = rl + p.inc_lo;
  unsigned long long nh = rh + p.inc_hi + (nl < rl ? 1ull : 0ull);
  p.lo = nl; p.hi = nh;
}
__device__ __forceinline__ unsigned long long pcg_next64(Pcg& p) {
  pcg_step(p);
  unsigned int rot = (unsigned int)(p.hi >> 58);
  unsigned long long x = p.hi ^ p.lo;
  return (x >> rot) | (x << ((64u - rot) & 63u));
}
__device__ __forceinline__ unsigned int pcg_next32(Pcg& p) {
  if (p.has32) { p.has32 = 0; return p.buf32; }
  unsigned long long n = pcg_next64(p);
  p.has32 = 1; p.buf32 = (unsigned int)(n >> 32);
  return (unsigned int)n;
}
__device__ __forceinline__ unsigned int lemire32(Pcg& p, unsigned int rng) {
  unsigned int rng_excl = rng + 1u;
  unsigned long long m = (unsigned long long)pcg_next32(p) * (unsigned long long)rng_excl;
  unsigned int leftover = (unsigned int)m;
  if (leftover < rng_excl) {
    unsigned int threshold = (0xffffffffu - rng) % rng_excl;
    while (leftover < threshold) {
      m = (unsigned long long)pcg_next32(p) * (unsigned long long)rng_excl;
      leftover = (unsigned int)m;
    }
  }
  return (unsigned int)(m >> 32);
}

__global__ void blockmap_kernel(int* __restrict__ blk_idx, float* __restrict__ dedup) {
  if (threadIdx.x != 0 || blockIdx.x != 0) return;
  unsigned int pool[4];
  unsigned int hc = 0x43b0d7e5u;
  auto ss_hash = [&hc](unsigned int val) {
    val ^= hc; hc *= 0x931e8875u; val *= hc; val ^= val >> 16; return val;
  };
  auto ss_mix = [](unsigned int x, unsigned int y) {
    unsigned int r = 0xca01f9ddu * x - 0x4973f715u * y;
    r ^= r >> 16; return r;
  };
  for (int i = 0; i < 4; ++i) pool[i] = ss_hash(0u);
  for (int s = 0; s < 4; ++s)
    for (int d = 0; d < 4; ++d)
      if (s != d) pool[d] = ss_mix(pool[d], ss_hash(pool[s]));
  unsigned int st32[8];
  unsigned int hb = 0x8b51f9ddu;
  for (int i = 0; i < 8; ++i) {
    unsigned int dv = pool[i & 3];
    dv ^= hb; hb *= 0x58f38dedu; dv *= hb; dv ^= dv >> 16;
    st32[i] = dv;
  }
  unsigned long long sd[4];
  for (int i = 0; i < 4; ++i)
    sd[i] = (unsigned long long)st32[2*i] | ((unsigned long long)st32[2*i+1] << 32);
  Pcg p;
  p.inc_hi = (sd[2] << 1) | (sd[3] >> 63);
  p.inc_lo = (sd[3] << 1) | 1ull;
  p.hi = 0ull; p.lo = 0ull;
  pcg_step(p);
  unsigned long long ol = p.lo;
  p.lo = ol + sd[1];
  p.hi = p.hi + sd[0] + (p.lo < ol ? 1ull : 0ull);
  pcg_step(p);
  p.has32 = 0; p.buf32 = 0;

  for (int i = 0; i < NB; ++i) {
    int lst[8];
    lst[0] = 0; lst[1] = NB - 1;
    lst[2] = (i > 0) ? i - 1 : 0;
    lst[3] = i;
    lst[4] = (i + 1 < NB - 1) ? i + 1 : NB - 1;
    bool excl[NB];
    for (int c = 0; c < NB; ++c) excl[c] = false;
    for (int j = 0; j < 5; ++j) excl[lst[j]] = true;
    int cand[NB], n = 0;
    for (int c = 0; c < NB; ++c) if (!excl[c]) cand[n++] = c;
    long long idx[3];
    unsigned long long hs[4] = {~0ull, ~0ull, ~0ull, ~0ull};
    for (int tI = 0; tI < 3; ++tI) {
      unsigned long long j = (unsigned long long)(n - 3 + tI);
      unsigned long long val = (unsigned long long)lemire32(p, (unsigned int)j);
      unsigned long long loc = val & 3ull;
      while (hs[loc] != ~0ull && hs[loc] != val) loc = (loc + 1ull) & 3ull;
      if (hs[loc] == ~0ull) { hs[loc] = val; idx[tI] = (long long)val; }
      else {
        loc = j & 3ull;
        while (hs[loc] != ~0ull) loc = (loc + 1ull) & 3ull;
        hs[loc] = j; idx[tI] = (long long)j;
      }
    }
    for (int fi = 2; fi >= 1; --fi) {
      int fj = (int)lemire32(p, (unsigned int)fi);
      long long tmpv = idx[fi]; idx[fi] = idx[fj]; idx[fj] = tmpv;
    }
    lst[5] = cand[idx[0]]; lst[6] = cand[idx[1]]; lst[7] = cand[idx[2]];

    unsigned int seen = 0u;
    for (int j = 0; j < 8; ++j) {
      blk_idx[i*8 + j] = lst[j];
      dedup[i*8 + j] = ((seen >> lst[j]) & 1u) ? 0.0f : 1.0f;
      seen |= (1u << lst[j]);
    }
  }
}

// ---------------------------------------------------------------------------
// Weight transpose+convert: src f32 [K][N] -> dst bf16 [Npad][K]
// ---------------------------------------------------------------------------
__global__ __launch_bounds__(256) void tconv_kernel(
    const float* __restrict__ src, unsigned short* __restrict__ dst,
    int K, int N, size_t src_stride, size_t dst_stride) {
  __shared__ float tile[64][65];
  src += (size_t)blockIdx.z * src_stride;
  dst += (size_t)blockIdx.z * dst_stride;
  int n0 = blockIdx.x * 64, k0 = blockIdx.y * 64;
  int t = threadIdx.x;
  int tr = t >> 4, tc = (t & 15) * 4;
  if ((N & 3) == 0 && n0 + 64 <= N) {
    #pragma unroll
    for (int i = 0; i < 4; ++i) {
      int k = k0 + tr + i * 16;
      float4 v = *reinterpret_cast<const float4*>(src + (size_t)k * N + n0 + tc);
      tile[tr + i*16][tc + 0] = v.x; tile[tr + i*16][tc + 1] = v.y;
      tile[tr + i*16][tc + 2] = v.z; tile[tr + i*16][tc + 3] = v.w;
    }
  } else if ((N & 1) == 0 && n0 + 64 <= N) {
    #pragma unroll
    for (int i = 0; i < 4; ++i) {
      int k = k0 + tr + i * 16;
      float2 v0 = *reinterpret_cast<const float2*>(src + (size_t)k * N + n0 + tc);
      float2 v1 = *reinterpret_cast<const float2*>(src + (size_t)k * N + n0 + tc + 2);
      tile[tr + i*16][tc + 0] = v0.x; tile[tr + i*16][tc + 1] = v0.y;
      tile[tr + i*16][tc + 2] = v1.x; tile[tr + i*16][tc + 3] = v1.y;
    }
  } else {
    for (int i = 0; i < 4; ++i) {
      int k = k0 + tr + i * 16;
      #pragma unroll
      for (int q2 = 0; q2 < 4; ++q2) {
        int n = n0 + tc + q2;
        tile[tr + i*16][tc + q2] = (n < N) ? src[(size_t)k * N + n] : 0.0f;
      }
    }
  }
  __syncthreads();
  int wr_ = t >> 2, wc_ = (t & 3) * 16;
  us8 w0, w1;
  #pragma unroll
  for (int j = 0; j < 8; ++j) {
    w0[j] = f2bf(tile[wc_ + j][wr_]);
    w1[j] = f2bf(tile[wc_ + 8 + j][wr_]);
  }
  size_t b = (size_t)(n0 + wr_) * K + k0 + wc_;
  *reinterpret_cast<us8*>(dst + b) = w0;
  *reinterpret_cast<us8*>(dst + b + 8) = w1;
}

__global__ void bias_cat_kernel(const float* __restrict__ bq, const float* __restrict__ bk,
                                const float* __restrict__ bv, float* __restrict__ dst) {
  int l = blockIdx.x;
  for (int i = threadIdx.x; i < QKVN; i += blockDim.x) {
    float v = (i < 768) ? bq[l*768 + i] : (i < 1536) ? bk[l*768 + i - 768] : bv[l*768 + i - 1536];
    dst[l*QKVN + i] = v;
  }
}

// ---------------------------------------------------------------------------
// LayerNorm
// ---------------------------------------------------------------------------
__device__ __forceinline__ float block_sum256(float v, float* red) {
  for (int off = 32; off > 0; off >>= 1) v += __shfl_down(v, off);
  int wv = threadIdx.x >> 6;
  if ((threadIdx.x & 63) == 0) red[wv] = v;
  __syncthreads();
  float r = red[0] + red[1] + red[2] + red[3];
  __syncthreads();
  return r;
}

__global__ void embed_ln_kernel(const int* __restrict__ ids, const int* __restrict__ tts,
                                const float* __restrict__ we, const float* __restrict__ pe,
                                const float* __restrict__ te, const float* __restrict__ lns,
                                const float* __restrict__ lnb, float* __restrict__ x,
                                unsigned short* __restrict__ xh) {
  __shared__ float red[4];
  int row = blockIdx.x, t = threadIdx.x;
  int id = ids[row], ty = tts[row];
  float e[3]; float s = 0.0f;
  for (int j = 0; j < 3; ++j) {
    int d = t + 256*j;
    e[j] = we[(size_t)id*DMODEL + d] + pe[(size_t)row*DMODEL + d] + te[(size_t)ty*DMODEL + d];
    s += e[j];
  }
  float mean = block_sum256(s, red) * (1.0f/768.0f);
  float vs = 0.0f;
  for (int j = 0; j < 3; ++j) { float dd = e[j] - mean; vs += dd*dd; }
  float var = block_sum256(vs, red) * (1.0f/768.0f);
  float inv = rsqrtf(var + 1e-12f);
  for (int j = 0; j < 3; ++j) {
    int d = t + 256*j;
    float val = (e[j] - mean) * inv * lns[d] + lnb[d];
    size_t idx = (size_t)row*DMODEL + d;
    x[idx] = val;
    xh[idx] = f2bf(val);
  }
}

// resln: e = x + a
__global__ void resln_kernel(float* __restrict__ x, const float* __restrict__ a,
                             const float* __restrict__ lns, const float* __restrict__ lnb,
                             unsigned short* __restrict__ xh) {
  __shared__ float red[4];
  int row = blockIdx.x, t = threadIdx.x;
  float e[3]; float s = 0.0f;
  for (int j = 0; j < 3; ++j) {
    int d = t + 256*j;
    e[j] = x[(size_t)row*DMODEL + d] + a[(size_t)row*DMODEL + d];
    s += e[j];
  }
  float mean = block_sum256(s, red) * (1.0f/768.0f);
  float vs = 0.0f;
  for (int j = 0; j < 3; ++j) { float dd = e[j] - mean; vs += dd*dd; }
  float var = block_sum256(vs, red) * (1.0f/768.0f);
  float inv = rsqrtf(var + 1e-12f);
  for (int j = 0; j < 3; ++j) {
    int d = t + 256*j;
    float val = (e[j] - mean) * inv * lns[d] + lnb[d];
    size_t idx = (size_t)row*DMODEL + d;
    x[idx] = val;
    xh[idx] = f2bf(val);
  }
}

// resln3: e = x + a0 + a1  (split-K partials)
__global__ void resln3_kernel(float* __restrict__ x, const float* __restrict__ a0,
                              const float* __restrict__ a1,
                              const float* __restrict__ lns, const float* __restrict__ lnb,
                              unsigned short* __restrict__ xh) {
  __shared__ float red[4];
  int row = blockIdx.x, t = threadIdx.x;
  float e[3]; float s = 0.0f;
  for (int j = 0; j < 3; ++j) {
    int d = t + 256*j;
    size_t idx = (size_t)row*DMODEL + d;
    e[j] = x[idx] + a0[idx] + a1[idx];
    s += e[j];
  }
  float mean = block_sum256(s, red) * (1.0f/768.0f);
  float vs = 0.0f;
  for (int j = 0; j < 3; ++j) { float dd = e[j] - mean; vs += dd*dd; }
  float var = block_sum256(vs, red) * (1.0f/768.0f);
  float inv = rsqrtf(var + 1e-12f);
  for (int j = 0; j < 3; ++j) {
    int d = t + 256*j;
    float val = (e[j] - mean) * inv * lns[d] + lnb[d];
    size_t idx = (size_t)row*DMODEL + d;
    x[idx] = val;
    xh[idx] = f2bf(val);
  }
}

// ---------------------------------------------------------------------------
// GEMM v15: bf16 A x bf16 B^T. Templated BM {64,128}, NBUF {3,4}, TN {64,128},
// SPLITK {0,1}. When SPLITK: K = half-K, LDA = full row stride, blockIdx.z
// selects K half; partial written to Cf + z*M*Nreal; bias only on z==0.
// ONE barrier per k-iter. m-fastest + bijective XCD-chunk swizzle.
// ---------------------------------------------------------------------------
template<int BM, int NBUF, int TN, int OMODE, int ACT, int SPLITK>
__global__ __launch_bounds__(256) void gemm15_kernel(
    const unsigned short* __restrict__ A_g, const unsigned short* __restrict__ Bt,
    const float* __restrict__ bias,
    float* __restrict__ Cf, unsigned short* __restrict__ Ch,
    int K, int Nreal, int LDA, int M) {
  __shared__ alignas(16) unsigned short As[NBUF][BM][32];
  __shared__ alignas(16) unsigned short Bs[NBUF][TN][32];
  constexpr int MFR = BM / 32;
  constexpr int NFR = TN / 32;
  constexpr int ACALLS = BM / 64;
  constexpr int BCALLS = TN / 64;
  constexpr int NLOADS = ACALLS + BCALLS;
  constexpr int DEPTH = NBUF - 2;
  int t = threadIdx.x;
  int mb = (int)gridDim.x;
  int nwg = mb * (int)gridDim.y;
  int lin = (int)blockIdx.x + mb * (int)blockIdx.y;
  int cpx = nwg >> 3;
  int nl = (lin & 7) * cpx + (lin >> 3);
  int m0 = (nl % mb) * BM, n0 = (nl / mb) * TN;
  int koff = SPLITK ? (int)blockIdx.z * K : 0;

  int wave = t >> 6, lane = t & 63, l16 = lane & 15, lk = lane >> 4;
  int wr = wave >> 1, wc = wave & 1;
  int row16 = lane >> 2, seg4 = lane & 3;
  const int srcoff = (seg4 ^ ((row16 >> 1) & 3)) * 8;
  const int swzrd = (lk ^ ((l16 >> 1) & 3)) * 8;

  const unsigned short* ag = A_g + (size_t)(m0 + wave*(BM/4) + row16) * LDA + koff + srcoff;
  const unsigned short* bg = Bt + (size_t)(n0 + wave*(TN/4) + row16) * LDA + koff + srcoff;
  const size_t K16 = (size_t)16 * LDA;

  auto STAGE = [&](int buf, int kit) {
    int k0 = kit << 5;
    #pragma unroll
    for (int j = 0; j < ACALLS; ++j)
      GLDS16(ag + (size_t)j * K16 + k0, &As[buf][wave*(BM/4) + 16*j][0]);
    #pragma unroll
    for (int j = 0; j < BCALLS; ++j)
      GLDS16(bg + (size_t)j * K16 + k0, &Bs[buf][wave*(TN/4) + 16*j][0]);
  };

  facc4 acc[MFR][NFR];
  #pragma unroll
  for (int mi = 0; mi < MFR; ++mi)
    #pragma unroll
    for (int ni = 0; ni < NFR; ++ni)
      acc[mi][ni] = (facc4){0.f, 0.f, 0.f, 0.f};

  const int nk = K >> 5;
  STAGE(0, 0);
  if constexpr (DEPTH == 2) STAGE(1, 1);
  int cur = 0;
  for (int it = 0; it < nk; ++it) {
    if constexpr (DEPTH == 2) {
      if (it + 2 < nk) {
        STAGE((cur + 2) % NBUF, it + 2);
        asm volatile("s_waitcnt vmcnt(%0)" :: "n"(2 * NLOADS) : "memory");
      } else if (it + 1 < nk) {
        asm volatile("s_waitcnt vmcnt(%0)" :: "n"(NLOADS) : "memory");
      } else {
        asm volatile("s_waitcnt vmcnt(0)" ::: "memory");
      }
    } else {
      if (it + 1 < nk) {
        STAGE((cur + 1) % NBUF, it + 1);
        asm volatile("s_waitcnt vmcnt(%0)" :: "n"(NLOADS) : "memory");
      } else {
        asm volatile("s_waitcnt vmcnt(0)" ::: "memory");
      }
    }
    __builtin_amdgcn_sched_barrier(0);
    __builtin_amdgcn_s_barrier();
    __builtin_amdgcn_sched_barrier(0);
    bfrag8 af[MFR], bf[NFR];
    #pragma unroll
    for (int mi = 0; mi < MFR; ++mi)
      af[mi] = *reinterpret_cast<const bfrag8*>(&As[cur][wr*(BM/2) + mi*16 + l16][swzrd]);
    #pragma unroll
    for (int ni = 0; ni < NFR; ++ni)
      bf[ni] = *reinterpret_cast<const bfrag8*>(&Bs[cur][wc*(TN/2) + ni*16 + l16][swzrd]);
    #pragma unroll
    for (int mi = 0; mi < MFR; ++mi)
      #pragma unroll
      for (int ni = 0; ni < NFR; ++ni)
        acc[mi][ni] = MFMA16(af[mi], bf[ni], acc[mi][ni]);
    cur = (cur + 1) % NBUF;
  }

  float* cfo = Cf;
  if constexpr (SPLITK) cfo = Cf + (size_t)blockIdx.z * (size_t)M * Nreal;
  bool dobias = !SPLITK || blockIdx.z == 0;

  #pragma unroll
  for (int mi = 0; mi < MFR; ++mi)
    #pragma unroll
    for (int ni = 0; ni < NFR; ++ni) {
      int col = n0 + wc*(TN/2) + ni*16 + l16;
      if (col >= Nreal) continue;
      float bv = dobias ? bias[col] : 0.0f;
      #pragma unroll
      for (int r2 = 0; r2 < 4; ++r2) {
        int row = m0 + wr*(BM/2) + mi*16 + lk*4 + r2;
        float val = acc[mi][ni][r2] + bv;
        if (ACT == 1) {
          float xx = val;
          val = 0.5f * xx * (1.0f + tanhf(0.7978845608028654f * (xx + 0.044715f * xx * xx * xx)));
        }
        size_t idx = (size_t)row * Nreal + col;
        if (OMODE == 0) cfo[idx] = val;
        else Ch[idx] = f2bf(val);
      }
    }
}

// ---------------------------------------------------------------------------
// Attention staging. K/Q: GLDS with XOR-swizzled source seg + matching read.
// ---------------------------------------------------------------------------
__device__ __forceinline__ void stage_glds64_swz(unsigned short (*dst)[64],
    const unsigned short* __restrict__ src, int ld, int t) {
  int w = t >> 6, lane = t & 63;
  int row8 = lane >> 3;
  int seg = (lane & 7) ^ (row8 & 7);
  const unsigned short* s = src + (size_t)(w*16 + row8) * ld + seg * 8;
  GLDS16(s, &dst[w*16][0]);
  GLDS16(s + (size_t)8 * ld, &dst[w*16 + 8][0]);
}

// ---------------------------------------------------------------------------
// Attention, merged sparse+global, bf16 operands, f32 online softmax (r19).
// ---------------------------------------------------------------------------
__global__ __launch_bounds__(256) void attn_kernel(
    const unsigned short* __restrict__ qkvh,
    const int* __restrict__ blk_idx, const float* __restrict__ dedup,
    const int* __restrict__ amask,
    unsigned short* __restrict__ ctxh,
    float* __restrict__ go, float* __restrict__ gm, float* __restrict__ gl) {
  __shared__ alignas(16) unsigned short Qs[64][64];
  __shared__ alignas(16) unsigned short KV2[2][64][64];
  __shared__ alignas(16) unsigned short Vs[64][66];
  __shared__ alignas(16) unsigned short Pt[64][68];
  int h = blockIdx.y;
  int bx = (int)blockIdx.x;
  const bool is_glob = (bx >= 30);
  int g = is_glob ? ((bx - 30) >> 2) : 0;
  int part = is_glob ? ((bx - 30) & 3) : 0;
  int qi = is_glob ? (g ? (NB - 1) : 0) : (bx + 1);
  int t = threadIdx.x, wave = t >> 6, lane = t & 63, l16 = lane & 15, lk = lane >> 4;
  const int swq0 = ((lk ^ (l16 & 7))) * 8;
  const int swq1 = (((4 + lk) ^ (l16 & 7))) * 8;
  const int vrow = t >> 2, vcolb = (t & 3) * 16;

  int barr[8];
  float addm[8][4];
  #pragma unroll
  for (int kb = 0; kb < 8; ++kb)
    barr[kb] = is_glob ? (part*8 + kb) : blk_idx[qi*NKB + kb];
  #pragma unroll
  for (int kb = 0; kb < 8; ++kb) {
    float dd = is_glob ? 1.0f : dedup[qi*NKB + kb];
    #pragma unroll
    for (int ni = 0; ni < 4; ++ni) {
      float mk = (float)amask[barr[kb]*64 + ni*16 + l16] * dd;
      addm[kb][ni] = (1.0f - mk) * (-1.0e9f);
    }
  }

  stage_glds64_swz(Qs, qkvh + (size_t)(qi*64)*QKVN + h*64, QKVN, t);
  __syncthreads();
  const bfrag8 q0 = *reinterpret_cast<const bfrag8*>(&Qs[wave*16 + l16][swq0]);
  const bfrag8 q1 = *reinterpret_cast<const bfrag8*>(&Qs[wave*16 + l16][swq1]);

  float mrow[4] = {-3.0e38f, -3.0e38f, -3.0e38f, -3.0e38f};
  float lrow[4] = {0.f, 0.f, 0.f, 0.f};
  facc4 o[4];
  #pragma unroll
  for (int ni = 0; ni < 4; ++ni) o[ni] = (facc4){0.f, 0.f, 0.f, 0.f};

  stage_glds64_swz(KV2[0], qkvh + (size_t)(barr[0]*64)*QKVN + DMODEL + h*64, QKVN, t);
  __builtin_amdgcn_sched_barrier(0);
  us8 vA0, vA1, vB0, vB1;
  {
    const unsigned short* vs0 = qkvh + (size_t)(barr[0]*64 + vrow)*QKVN + 2*DMODEL + h*64 + vcolb;
    vA0 = *reinterpret_cast<const us8*>(vs0);
    vA1 = *reinterpret_cast<const us8*>(vs0 + 8);
  }

  auto body = [&](int kb, const us8& vc0, const us8& vc1, us8& vn0, us8& vn1) {
    if (kb + 1 < 8) {
      int bn = barr[kb + 1];
      stage_glds64_swz(KV2[(kb + 1) & 1], qkvh + (size_t)(bn*64)*QKVN + DMODEL + h*64, QKVN, t);
      __builtin_amdgcn_sched_barrier(0);
      const unsigned short* vsn = qkvh + (size_t)(bn*64 + vrow)*QKVN + 2*DMODEL + h*64 + vcolb;
      vn0 = *reinterpret_cast<const us8*>(vsn);
      vn1 = *reinterpret_cast<const us8*>(vsn + 8);
      asm volatile("s_waitcnt vmcnt(4)" ::: "memory");
    } else {
      asm volatile("s_waitcnt vmcnt(0)" ::: "memory");
    }
    __builtin_amdgcn_sched_barrier(0);
    __builtin_amdgcn_s_barrier();
    __builtin_amdgcn_sched_barrier(0);
    float s[4][4];
    #pragma unroll
    for (int ni = 0; ni < 4; ++ni) {
      bfrag8 k0 = *reinterpret_cast<const bfrag8*>(&KV2[kb & 1][ni*16 + l16][swq0]);
      bfrag8 k1 = *reinterpret_cast<const bfrag8*>(&KV2[kb & 1][ni*16 + l16][swq1]);
      facc4 sa = (facc4){0.f, 0.f, 0.f, 0.f};
      sa = MFMA16(q0, k0, sa);
      sa = MFMA16(q1, k1, sa);
      #pragma unroll
      for (int r = 0; r < 4; ++r) s[ni][r] = sa[r] * 0.125f + addm[kb][ni];
    }
    float pexp[4][4];
    #pragma unroll
    for (int r = 0; r < 4; ++r) {
      float tm = fmaxf(fmaxf(s[0][r], s[1][r]), fmaxf(s[2][r], s[3][r]));
      tm = fmaxf(tm, __shfl_xor(tm, 1));
      tm = fmaxf(tm, __shfl_xor(tm, 2));
      tm = fmaxf(tm, __shfl_xor(tm, 4));
      tm = fmaxf(tm, __shfl_xor(tm, 8));
      float mn = fmaxf(mrow[r], tm);
      float f = expf(mrow[r] - mn);
      #pragma unroll
      for (int ni = 0; ni < 4; ++ni) o[ni][r] *= f;
      float ps = 0.0f;
      #pragma unroll
      for (int ni = 0; ni < 4; ++ni) { pexp[ni][r] = expf(s[ni][r] - mn); ps += pexp[ni][r]; }
      ps += __shfl_xor(ps, 1);
      ps += __shfl_xor(ps, 2);
      ps += __shfl_xor(ps, 4);
      ps += __shfl_xor(ps, 8);
      lrow[r] = lrow[r] * f + ps;
      mrow[r] = mn;
    }
    #pragma unroll
    for (int ni = 0; ni < 4; ++ni)
      #pragma unroll
      for (int r = 0; r < 4; ++r)
        Pt[wave*16 + lk*4 + r][ni*16 + l16] = f2bf(pexp[ni][r]);
    #pragma unroll
    for (int j = 0; j < 8; ++j) {
      Vs[vcolb + j][vrow] = vc0[j];
      Vs[vcolb + 8 + j][vrow] = vc1[j];
    }
    asm volatile("s_waitcnt lgkmcnt(0)" ::: "memory");
    __builtin_amdgcn_sched_barrier(0);
    __builtin_amdgcn_s_barrier();
    __builtin_amdgcn_sched_barrier(0);
    #pragma unroll
    for (int kc = 0; kc < 2; ++kc) {
      bfrag8 ph = *reinterpret_cast<const bfrag8*>(&Pt[wave*16 + l16][kc*32 + lk*8]);
      #pragma unroll
      for (int ni = 0; ni < 4; ++ni) {
        bfrag8 vh = *reinterpret_cast<const bfrag8*>(&Vs[ni*16 + l16][kc*32 + lk*8]);
        o[ni] = MFMA16(ph, vh, o[ni]);
      }
    }
  };

  body(0, vA0, vA1, vB0, vB1);
  body(1, vB0, vB1, vA0, vA1);
  body(2, vA0, vA1, vB0, vB1);
  body(3, vB0, vB1, vA0, vA1);
  body(4, vA0, vA1, vB0, vB1);
  body(5, vB0, vB1, vA0, vA1);
  body(6, vA0, vA1, vB0, vB1);
  body(7, vB0, vB1, vA0, vA1);

  if (!is_glob) {
    float invl[4];
    #pragma unroll
    for (int r = 0; r < 4; ++r) invl[r] = 1.0f / lrow[r];
    #pragma unroll
    for (int ni = 0; ni < 4; ++ni)
      #pragma unroll
      for (int r = 0; r < 4; ++r) {
        int row = qi*64 + wave*16 + lk*4 + r;
        int col = h*64 + ni*16 + l16;
        ctxh[(size_t)row*DMODEL + col] = f2bf(o[ni][r] * invl[r]);
      }
  } else {
    int pidx = (g * NHEAD + h) * 4 + part;
    float* gob = go + (size_t)pidx * 64 * 64;
    #pragma unroll
    for (int ni = 0; ni < 4; ++ni)
      #pragma unroll
      for (int r = 0; r < 4; ++r)
        gob[(wave*16 + lk*4 + r) * 64 + ni*16 + l16] = o[ni][r];
    if (l16 == 0) {
      #pragma unroll
      for (int r = 0; r < 4; ++r) {
        int row = wave*16 + lk*4 + r;
        gm[pidx*64 + row] = mrow[r];
        gl[pidx*64 + row] = lrow[r];
      }
    }
  }
}

__global__ __launch_bounds__(256) void gattn_comb_kernel(
    const float* __restrict__ go, const float* __restrict__ gm,
    const float* __restrict__ gl, unsigned short* __restrict__ ctxh) {
  int g = blockIdx.x, h = blockIdx.y;
  int t = threadIdx.x;
  int row = t >> 2, cseg = (t & 3) * 16;
  int base = (g * NHEAD + h) * 4;
  float m = -3.0e38f;
  for (int p = 0; p < 4; ++p) m = fmaxf(m, gm[(base + p)*64 + row]);
  float w[4]; float l = 0.0f;
  for (int p = 0; p < 4; ++p) {
    w[p] = expf(gm[(base + p)*64 + row] - m);
    l += gl[(base + p)*64 + row] * w[p];
  }
  float inv = 1.0f / l;
  int qrow = (g ? (NB - 1) * 64 : 0) + row;
  for (int c = 0; c < 16; ++c) {
    float acc = 0.0f;
    for (int p = 0; p < 4; ++p)
      acc += go[((size_t)(base + p)*64 + row)*64 + cseg + c] * w[p];
    ctxh[(size_t)qrow*DMODEL + h*64 + cseg + c] = f2bf(acc * inv);
  }
}

// ---------------------------------------------------------------------------
// Launch
// ---------------------------------------------------------------------------
extern "C" void kernel_launch(void* const* d_in, const int* in_sizes, int n_in,
                              void* d_out, int out_size, void* d_ws, size_t ws_size,
                              hipStream_t stream) {
  const int*   input_ids  = (const int*)d_in[0];
  const int*   attn_mask  = (const int*)d_in[1];
  const int*   token_type = (const int*)d_in[2];
  const float* word_emb   = (const float*)d_in[3];
  const float* pos_emb    = (const float*)d_in[4];
  const float* type_emb   = (const float*)d_in[5];
  const float* emb_ln_s   = (const float*)d_in[6];
  const float* emb_ln_b   = (const float*)d_in[7];
  const float* Wq = (const float*)d_in[8];
  const float* Wk = (const float*)d_in[9];
  const float* Wv = (const float*)d_in[10];
  const float* bq = (const float*)d_in[11];
  const float* bk = (const float*)d_in[12];
  const float* bv = (const float*)d_in[13];
  const float* Wo = (const float*)d_in[14];
  const float* bo = (const float*)d_in[15];
  const float* ln1_s = (const float*)d_in[16];
  const float* ln1_b = (const float*)d_in[17];
  const float* W1 = (const float*)d_in[18];
  const float* b1 = (const float*)d_in[19];
  const float* W2 = (const float*)d_in[20];
  const float* b2 = (const float*)d_in[21];
  const float* ln2_s = (const float*)d_in[22];
  const float* ln2_b = (const float*)d_in[23];
  const float* fc_w = (const float*)d_in[24];
  const float* fc_b = (const float*)d_in[25];
  float* out = (float*)d_out;

  unsigned char* base = (unsigned char*)d_ws;
  size_t off = 0;
  auto carve = [&](size_t bytes) -> void* {
    void* p = base + off;
    off = (off + bytes + 255) & ~(size_t)255;
    return p;
  };
  int*   blk_i = (int*)carve(256 * 4);
  float* dedup = (float*)carve(256 * 4);
  float* bqkv  = (float*)carve((size_t)NLAYER * QKVN * 4);
  float* x     = (float*)carve((size_t)S_LEN * DMODEL * 4);
  float* tmp   = (float*)carve((size_t)2 * S_LEN * DMODEL * 4);   // 2 halves for split-K
  unsigned short* xh   = (unsigned short*)carve((size_t)S_LEN * DMODEL * 2);
  unsigned short* qkvh = (unsigned short*)carve((size_t)S_LEN * QKVN * 2);
  unsigned short* ctxh = (unsigned short*)carve((size_t)S_LEN * DMODEL * 2);
  unsigned short* hbh  = (unsigned short*)carve((size_t)S_LEN * FFDIM * 2);
  float* go    = (float*)carve((size_t)2 * NHEAD * 4 * 64 * 64 * 4);
  float* gm    = (float*)carve((size_t)2 * NHEAD * 4 * 64 * 4);
  float* gl    = (float*)carve((size_t)2 * NHEAD * 4 * 64 * 4);
  unsigned short* qkvT = (unsigned short*)carve((size_t)NLAYER * QKVN * DMODEL * 2);
  unsigned short* woT  = (unsigned short*)carve((size_t)NLAYER * DMODEL * DMODEL * 2);
  unsigned short* w1T  = (unsigned short*)carve((size_t)NLAYER * FFDIM * DMODEL * 2);
  unsigned short* w2T  = (unsigned short*)carve((size_t)NLAYER * DMODEL * FFDIM * 2);
  unsigned short* fcT  = (unsigned short*)carve((size_t)VPAD * DMODEL * 2);

  blockmap_kernel<<<1, 1, 0, stream>>>(blk_i, dedup);

  const size_t DD = (size_t)DMODEL * DMODEL;
  const size_t SD = (size_t)S_LEN * DMODEL;
  dim3 g768(12, 12, NLAYER);
  tconv_kernel<<<g768, 256, 0, stream>>>(Wq, qkvT + 0,            DMODEL, DMODEL, DD, (size_t)QKVN * DMODEL);
  tconv_kernel<<<g768, 256, 0, stream>>>(Wk, qkvT + 768 * DMODEL, DMODEL, DMODEL, DD, (size_t)QKVN * DMODEL);
  tconv_kernel<<<g768, 256, 0, stream>>>(Wv, qkvT + 1536 * DMODEL,DMODEL, DMODEL, DD, (size_t)QKVN * DMODEL);
  tconv_kernel<<<g768, 256, 0, stream>>>(Wo, woT, DMODEL, DMODEL, DD, DD);
  tconv_kernel<<<dim3(48, 12, NLAYER), 256, 0, stream>>>(W1, w1T, DMODEL, FFDIM, (size_t)DMODEL * FFDIM, (size_t)FFDIM * DMODEL);
  tconv_kernel<<<dim3(12, 48, NLAYER), 256, 0, stream>>>(W2, w2T, FFDIM, DMODEL, (size_t)FFDIM * DMODEL, (size_t)DMODEL * FFDIM);
  tconv_kernel<<<dim3(VPAD / 64, 12, 1), 256, 0, stream>>>(fc_w, fcT, DMODEL, VOCAB, 0, 0);
  bias_cat_kernel<<<NLAYER, 256, 0, stream>>>(bq, bk, bv, bqkv);

  embed_ln_kernel<<<S_LEN, 256, 0, stream>>>(input_ids, token_type, word_emb, pos_emb,
                                             type_emb, emb_ln_s, emb_ln_b, x, xh);

  for (int l = 0; l < NLAYER; ++l) {
    gemm15_kernel<64, 4, 128, 2, 0, 0><<<dim3(32, QKVN/128), 256, 0, stream>>>(
        xh, qkvT + (size_t)l * QKVN * DMODEL, bqkv + (size_t)l * QKVN,
        nullptr, qkvh, DMODEL, QKVN, DMODEL, S_LEN);

    attn_kernel<<<dim3(38, NHEAD), 256, 0, stream>>>(
        qkvh, blk_i, dedup, attn_mask, ctxh, go, gm, gl);
    gattn_comb_kernel<<<dim3(2, NHEAD), 256, 0, stream>>>(go, gm, gl, ctxh);

    // Wo: split-K x2 -> partials tmp[0..SD), tmp[SD..2SD)
    gemm15_kernel<64, 4, 64, 0, 0, 1><<<dim3(32, DMODEL/64, 2), 256, 0, stream>>>(
        ctxh, woT + (size_t)l * DD, bo + (size_t)l * DMODEL,
        tmp, nullptr, DMODEL/2, DMODEL, DMODEL, S_LEN);
    resln3_kernel<<<S_LEN, 256, 0, stream>>>(x, tmp, tmp + SD,
                                             ln1_s + l*DMODEL, ln1_b + l*DMODEL, xh);

    gemm15_kernel<64, 4, 128, 2, 1, 0><<<dim3(32, FFDIM/128), 256, 0, stream>>>(
        xh, w1T + (size_t)l * FFDIM * DMODEL, b1 + (size_t)l * FFDIM,
        nullptr, hbh, DMODEL, FFDIM, DMODEL, S_LEN);
    // FF2: split-K x2 -> partials tmp[0..SD), tmp[SD..2SD)
    gemm15_kernel<64, 4, 64, 0, 0, 1><<<dim3(32, DMODEL/64, 2), 256, 0, stream>>>(
        hbh, w2T + (size_t)l * DMODEL * FFDIM, b2 + (size_t)l * DMODEL,
        tmp, nullptr, FFDIM/2, DMODEL, FFDIM, S_LEN);
    resln3_kernel<<<S_LEN, 256, 0, stream>>>(x, tmp, tmp + SD,
                                             ln2_s + l*DMODEL, ln2_b + l*DMODEL, xh);
  }

  gemm15_kernel<128, 3, 128, 0, 0, 0><<<dim3(16, VPAD/128), 256, 0, stream>>>(
      xh, fcT, fc_b, out, nullptr, DMODEL, VOCAB, DMODEL, S_LEN);
}

// Round 25
// 2174.082 us; speedup vs baseline: 1.1430x; 1.0053x over previous
//
#include <hip/hip_runtime.h>
#include <hip/hip_bf16.h>

// ---------------------------------------------------------------------------
// BigBird forward. bf16 A/B GEMMs (r19-best tiles), Wo+FF2 split-K x2,
// vocab GEMM 512-thread BM=256 (16 waves/CU). ONE barrier/iter, m-fastest +
// bijective XCD swizzle. Attention: K dbuf + stage-1-ahead counted vmcnt.
// ---------------------------------------------------------------------------

#define S_LEN 2048
#define DMODEL 768
#define FFDIM 3072
#define VOCAB 50358
#define VPAD  50432
#define NLAYER 12
#define NHEAD 12
#define NB 32
#define NKB 8
#define QKVN 2304

typedef __attribute__((ext_vector_type(8))) short bfrag8;
typedef __attribute__((ext_vector_type(8))) unsigned short us8;
typedef __attribute__((ext_vector_type(4))) float facc4;

__device__ __forceinline__ unsigned short f2bf(float f) {
  unsigned int u = __builtin_bit_cast(unsigned int, f);
  u += 0x7fffu + ((u >> 16) & 1u);
  return (unsigned short)(u >> 16);
}
__device__ __forceinline__ float bf2f(unsigned short h) {
  unsigned int u = ((unsigned int)h) << 16;
  return __builtin_bit_cast(float, u);
}

#define MFMA16(a, b, c) __builtin_amdgcn_mfma_f32_16x16x32_bf16((a), (b), (c), 0, 0, 0)
#define GLDS16(g, l) __builtin_amdgcn_global_load_lds( \
    (const __attribute__((address_space(1))) void*)(g), \
    (__attribute__((address_space(3))) void*)(l), 16, 0, 0)

// ---------------------------------------------------------------------------
// numpy RNG replication (validated: passes)
// ---------------------------------------------------------------------------
struct Pcg {
  unsigned long long hi, lo, inc_hi, inc_lo;
  int has32; unsigned int buf32;
};

__device__ __forceinline__ void pcg_step(Pcg& p) {
  const unsigned long long MH = 0x2360ed051fc65da4ull;
  const unsigned long long ML = 0x4385df649fccf645ull;
  unsigned long long rl = p.lo * ML;
  unsigned long long rh = __umul64hi(p.lo, ML) + p.lo * MH + p.hi * ML;
  unsigned long long nl = rl + p.inc_lo;
  unsigned long long nh = rh + p.inc_hi + (nl < rl ? 1ull : 0ull);
  p.lo = nl; p.hi = nh;
}
__device__ __forceinline__ unsigned long long pcg_next64(Pcg& p) {
  pcg_step(p);
  unsigned int rot = (unsigned int)(p.hi >> 58);
  unsigned long long x = p.hi ^ p.lo;
  return (x >> rot) | (x << ((64u - rot) & 63u));
}
__device__ __forceinline__ unsigned int pcg_next32(Pcg& p) {
  if (p.has32) { p.has32 = 0; return p.buf32; }
  unsigned long long n = pcg_next64(p);
  p.has32 = 1; p.buf32 = (unsigned int)(n >> 32);
  return (unsigned int)n;
}
__device__ __forceinline__ unsigned int lemire32(Pcg& p, unsigned int rng) {
  unsigned int rng_excl = rng + 1u;
  unsigned long long m = (unsigned long long)pcg_next32(p) * (unsigned long long)rng_excl;
  unsigned int leftover = (unsigned int)m;
  if (leftover < rng_excl) {
    unsigned int threshold = (0xffffffffu - rng) % rng_excl;
    while (leftover < threshold) {
      m = (unsigned long long)pcg_next32(p) * (unsigned long long)rng_excl;
      leftover = (unsigned int)m;
    }
  }
  return (unsigned int)(m >> 32);
}

__global__ void blockmap_kernel(int* __restrict__ blk_idx, float* __restrict__ dedup) {
  if (threadIdx.x != 0 || blockIdx.x != 0) return;
  unsigned int pool[4];
  unsigned int hc = 0x43b0d7e5u;
  auto ss_hash = [&hc](unsigned int val) {
    val ^= hc; hc *= 0x931e8875u; val *= hc; val ^= val >> 16; return val;
  };
  auto ss_mix = [](unsigned int x, unsigned int y) {
    unsigned int r = 0xca01f9ddu * x - 0x4973f715u * y;
    r ^= r >> 16; return r;
  };
  for (int i = 0; i < 4; ++i) pool[i] = ss_hash(0u);
  for (int s = 0; s < 4; ++s)
    for (int d = 0; d < 4; ++d)
      if (s != d) pool[d] = ss_mix(pool[d], ss_hash(pool[s]));
  unsigned int st32[8];
  unsigned int hb = 0x8b51f9ddu;
  for (int i = 0; i < 8; ++i) {
    unsigned int dv = pool[i & 3];
    dv ^= hb; hb *= 0x58f38dedu; dv *= hb; dv ^= dv >> 16;
    st32[i] = dv;
  }
  unsigned long long sd[4];
  for (int i = 0; i < 4; ++i)
    sd[i] = (unsigned long long)st32[2*i] | ((unsigned long long)st32[2*i+1] << 32);
  Pcg p;
  p.inc_hi = (sd[2] << 1) | (sd[3] >> 63);
  p.inc_lo = (sd[3] << 1) | 1ull;
  p.hi = 0ull; p.lo = 0ull;
  pcg_step(p);
  unsigned long long ol = p.lo;
  p.lo = ol + sd[1];
  p.hi = p.hi + sd[0] + (p.lo < ol ? 1ull : 0ull);
  pcg_step(p);
  p.has32 = 0; p.buf32 = 0;

  for (int i = 0; i < NB; ++i) {
    int lst[8];
    lst[0] = 0; lst[1] = NB - 1;
    lst[2] = (i > 0) ? i - 1 : 0;
    lst[3] = i;
    lst[4] = (i + 1 < NB - 1) ? i + 1 : NB - 1;
    bool excl[NB];
    for (int c = 0; c < NB; ++c) excl[c] = false;
    for (int j = 0; j < 5; ++j) excl[lst[j]] = true;
    int cand[NB], n = 0;
    for (int c = 0; c < NB; ++c) if (!excl[c]) cand[n++] = c;
    long long idx[3];
    unsigned long long hs[4] = {~0ull, ~0ull, ~0ull, ~0ull};
    for (int tI = 0; tI < 3; ++tI) {
      unsigned long long j = (unsigned long long)(n - 3 + tI);
      unsigned long long val = (unsigned long long)lemire32(p, (unsigned int)j);
      unsigned long long loc = val & 3ull;
      while (hs[loc] != ~0ull && hs[loc] != val) loc = (loc + 1ull) & 3ull;
      if (hs[loc] == ~0ull) { hs[loc] = val; idx[tI] = (long long)val; }
      else {
        loc = j & 3ull;
        while (hs[loc] != ~0ull) loc = (loc + 1ull) & 3ull;
        hs[loc] = j; idx[tI] = (long long)j;
      }
    }
    for (int fi = 2; fi >= 1; --fi) {
      int fj = (int)lemire32(p, (unsigned int)fi);
      long long tmpv = idx[fi]; idx[fi] = idx[fj]; idx[fj] = tmpv;
    }
    lst[5] = cand[idx[0]]; lst[6] = cand[idx[1]]; lst[7] = cand[idx[2]];

    unsigned int seen = 0u;
    for (int j = 0; j < 8; ++j) {
      blk_idx[i*8 + j] = lst[j];
      dedup[i*8 + j] = ((seen >> lst[j]) & 1u) ? 0.0f : 1.0f;
      seen |= (1u << lst[j]);
    }
  }
}

// ---------------------------------------------------------------------------
// Weight transpose+convert: src f32 [K][N] -> dst bf16 [Npad][K]
// ---------------------------------------------------------------------------
__global__ __launch_bounds__(256) void tconv_kernel(
    const float* __restrict__ src, unsigned short* __restrict__ dst,
    int K, int N, size_t src_stride, size_t dst_stride) {
  __shared__ float tile[64][65];
  src += (size_t)blockIdx.z * src_stride;
  dst += (size_t)blockIdx.z * dst_stride;
  int n0 = blockIdx.x * 64, k0 = blockIdx.y * 64;
  int t = threadIdx.x;
  int tr = t >> 4, tc = (t & 15) * 4;
  if ((N & 3) == 0 && n0 + 64 <= N) {
    #pragma unroll
    for (int i = 0; i < 4; ++i) {
      int k = k0 + tr + i * 16;
      float4 v = *reinterpret_cast<const float4*>(src + (size_t)k * N + n0 + tc);
      tile[tr + i*16][tc + 0] = v.x; tile[tr + i*16][tc + 1] = v.y;
      tile[tr + i*16][tc + 2] = v.z; tile[tr + i*16][tc + 3] = v.w;
    }
  } else if ((N & 1) == 0 && n0 + 64 <= N) {
    #pragma unroll
    for (int i = 0; i < 4; ++i) {
      int k = k0 + tr + i * 16;
      float2 v0 = *reinterpret_cast<const float2*>(src + (size_t)k * N + n0 + tc);
      float2 v1 = *reinterpret_cast<const float2*>(src + (size_t)k * N + n0 + tc + 2);
      tile[tr + i*16][tc + 0] = v0.x; tile[tr + i*16][tc + 1] = v0.y;
      tile[tr + i*16][tc + 2] = v1.x; tile[tr + i*16][tc + 3] = v1.y;
    }
  } else {
    for (int i = 0; i < 4; ++i) {
      int k = k0 + tr + i * 16;
      #pragma unroll
      for (int q2 = 0; q2 < 4; ++q2) {
        int n = n0 + tc + q2;
        tile[tr + i*16][tc + q2] = (n < N) ? src[(size_t)k * N + n] : 0.0f;
      }
    }
  }
  __syncthreads();
  int wr_ = t >> 2, wc_ = (t & 3) * 16;
  us8 w0, w1;
  #pragma unroll
  for (int j = 0; j < 8; ++j) {
    w0[j] = f2bf(tile[wc_ + j][wr_]);
    w1[j] = f2bf(tile[wc_ + 8 + j][wr_]);
  }
  size_t b = (size_t)(n0 + wr_) * K + k0 + wc_;
  *reinterpret_cast<us8*>(dst + b) = w0;
  *reinterpret_cast<us8*>(dst + b + 8) = w1;
}

__global__ void bias_cat_kernel(const float* __restrict__ bq, const float* __restrict__ bk,
                                const float* __restrict__ bv, float* __restrict__ dst) {
  int l = blockIdx.x;
  for (int i = threadIdx.x; i < QKVN; i += blockDim.x) {
    float v = (i < 768) ? bq[l*768 + i] : (i < 1536) ? bk[l*768 + i - 768] : bv[l*768 + i - 1536];
    dst[l*QKVN + i] = v;
  }
}

// ---------------------------------------------------------------------------
// LayerNorm
// ---------------------------------------------------------------------------
__device__ __forceinline__ float block_sum256(float v, float* red) {
  for (int off = 32; off > 0; off >>= 1) v += __shfl_down(v, off);
  int wv = threadIdx.x >> 6;
  if ((threadIdx.x & 63) == 0) red[wv] = v;
  __syncthreads();
  float r = red[0] + red[1] + red[2] + red[3];
  __syncthreads();
  return r;
}

__global__ void embed_ln_kernel(const int* __restrict__ ids, const int* __restrict__ tts,
                                const float* __restrict__ we, const float* __restrict__ pe,
                                const float* __restrict__ te, const float* __restrict__ lns,
                                const float* __restrict__ lnb, float* __restrict__ x,
                                unsigned short* __restrict__ xh) {
  __shared__ float red[4];
  int row = blockIdx.x, t = threadIdx.x;
  int id = ids[row], ty = tts[row];
  float e[3]; float s = 0.0f;
  for (int j = 0; j < 3; ++j) {
    int d = t + 256*j;
    e[j] = we[(size_t)id*DMODEL + d] + pe[(size_t)row*DMODEL + d] + te[(size_t)ty*DMODEL + d];
    s += e[j];
  }
  float mean = block_sum256(s, red) * (1.0f/768.0f);
  float vs = 0.0f;
  for (int j = 0; j < 3; ++j) { float dd = e[j] - mean; vs += dd*dd; }
  float var = block_sum256(vs, red) * (1.0f/768.0f);
  float inv = rsqrtf(var + 1e-12f);
  for (int j = 0; j < 3; ++j) {
    int d = t + 256*j;
    float val = (e[j] - mean) * inv * lns[d] + lnb[d];
    size_t idx = (size_t)row*DMODEL + d;
    x[idx] = val;
    xh[idx] = f2bf(val);
  }
}

// resln: e = x + a
__global__ void resln_kernel(float* __restrict__ x, const float* __restrict__ a,
                             const float* __restrict__ lns, const float* __restrict__ lnb,
                             unsigned short* __restrict__ xh) {
  __shared__ float red[4];
  int row = blockIdx.x, t = threadIdx.x;
  float e[3]; float s = 0.0f;
  for (int j = 0; j < 3; ++j) {
    int d = t + 256*j;
    e[j] = x[(size_t)row*DMODEL + d] + a[(size_t)row*DMODEL + d];
    s += e[j];
  }
  float mean = block_sum256(s, red) * (1.0f/768.0f);
  float vs = 0.0f;
  for (int j = 0; j < 3; ++j) { float dd = e[j] - mean; vs += dd*dd; }
  float var = block_sum256(vs, red) * (1.0f/768.0f);
  float inv = rsqrtf(var + 1e-12f);
  for (int j = 0; j < 3; ++j) {
    int d = t + 256*j;
    float val = (e[j] - mean) * inv * lns[d] + lnb[d];
    size_t idx = (size_t)row*DMODEL + d;
    x[idx] = val;
    xh[idx] = f2bf(val);
  }
}

// resln3: e = x + a0 + a1  (split-K partials)
__global__ void resln3_kernel(float* __restrict__ x, const float* __restrict__ a0,
                              const float* __restrict__ a1,
                              const float* __restrict__ lns, const float* __restrict__ lnb,
                              unsigned short* __restrict__ xh) {
  __shared__ float red[4];
  int row = blockIdx.x, t = threadIdx.x;
  float e[3]; float s = 0.0f;
  for (int j = 0; j < 3; ++j) {
    int d = t + 256*j;
    size_t idx = (size_t)row*DMODEL + d;
    e[j] = x[idx] + a0[idx] + a1[idx];
    s += e[j];
  }
  float mean = block_sum256(s, red) * (1.0f/768.0f);
  float vs = 0.0f;
  for (int j = 0; j < 3; ++j) { float dd = e[j] - mean; vs += dd*dd; }
  float var = block_sum256(vs, red) * (1.0f/768.0f);
  float inv = rsqrtf(var + 1e-12f);
  for (int j = 0; j < 3; ++j) {
    int d = t + 256*j;
    float val = (e[j] - mean) * inv * lns[d] + lnb[d];
    size_t idx = (size_t)row*DMODEL + d;
    x[idx] = val;
    xh[idx] = f2bf(val);
  }
}

// ---------------------------------------------------------------------------
// GEMM v16: bf16 A x bf16 B^T. Templated BM, NBUF {3,4}, TN {64,128},
// SPLITK {0,1}, NW = waves/block {4,8}. Waves arranged (NW/2) x 2.
// Per-wave: MFR = BM/(8*NW) m-fragments, NFR = TN/32 n-fragments.
// Staging: each wave stages BM/NW rows of A, TN/NW rows of B per k-iter.
// ONE barrier per k-iter. m-fastest + bijective XCD-chunk swizzle.
// ---------------------------------------------------------------------------
template<int BM, int NBUF, int TN, int OMODE, int ACT, int SPLITK, int NW>
__global__ __launch_bounds__(NW * 64) void gemm16_kernel(
    const unsigned short* __restrict__ A_g, const unsigned short* __restrict__ Bt,
    const float* __restrict__ bias,
    float* __restrict__ Cf, unsigned short* __restrict__ Ch,
    int K, int Nreal, int LDA, int M) {
  __shared__ alignas(16) unsigned short As[NBUF][BM][32];
  __shared__ alignas(16) unsigned short Bs[NBUF][TN][32];
  constexpr int MFR = BM / (8 * NW);          // m-fragments per wave
  constexpr int NFR = TN / 32;                // n-fragments per wave
  constexpr int ACALLS = BM / (16 * NW);
  constexpr int BCALLS = TN / (16 * NW);
  constexpr int NLOADS = ACALLS + BCALLS;
  constexpr int DEPTH = NBUF - 2;
  constexpr int WROWS = BM / (NW / 2);        // rows per wr slot
  int t = threadIdx.x;
  int mb = (int)gridDim.x;
  int nwg = mb * (int)gridDim.y;
  int lin = (int)blockIdx.x + mb * (int)blockIdx.y;
  int cpx = nwg >> 3;
  int nl = (lin & 7) * cpx + (lin >> 3);
  int m0 = (nl % mb) * BM, n0 = (nl / mb) * TN;
  int koff = SPLITK ? (int)blockIdx.z * K : 0;

  int wave = t >> 6, lane = t & 63, l16 = lane & 15, lk = lane >> 4;
  int wr = wave >> 1, wc = wave & 1;
  int row16 = lane >> 2, seg4 = lane & 3;
  const int srcoff = (seg4 ^ ((row16 >> 1) & 3)) * 8;
  const int swzrd = (lk ^ ((l16 >> 1) & 3)) * 8;

  const unsigned short* ag = A_g + (size_t)(m0 + wave*(BM/NW) + row16) * LDA + koff + srcoff;
  const unsigned short* bg = Bt + (size_t)(n0 + wave*(TN/NW) + row16) * LDA + koff + srcoff;
  const size_t K16 = (size_t)16 * LDA;

  auto STAGE = [&](int buf, int kit) {
    int k0 = kit << 5;
    #pragma unroll
    for (int j = 0; j < ACALLS; ++j)
      GLDS16(ag + (size_t)j * K16 + k0, &As[buf][wave*(BM/NW) + 16*j][0]);
    #pragma unroll
    for (int j = 0; j < BCALLS; ++j)
      GLDS16(bg + (size_t)j * K16 + k0, &Bs[buf][wave*(TN/NW) + 16*j][0]);
  };

  facc4 acc[MFR][NFR];
  #pragma unroll
  for (int mi = 0; mi < MFR; ++mi)
    #pragma unroll
    for (int ni = 0; ni < NFR; ++ni)
      acc[mi][ni] = (facc4){0.f, 0.f, 0.f, 0.f};

  const int nk = K >> 5;
  STAGE(0, 0);
  if constexpr (DEPTH == 2) STAGE(1, 1);
  int cur = 0;
  for (int it = 0; it < nk; ++it) {
    if constexpr (DEPTH == 2) {
      if (it + 2 < nk) {
        STAGE((cur + 2) % NBUF, it + 2);
        asm volatile("s_waitcnt vmcnt(%0)" :: "n"(2 * NLOADS) : "memory");
      } else if (it + 1 < nk) {
        asm volatile("s_waitcnt vmcnt(%0)" :: "n"(NLOADS) : "memory");
      } else {
        asm volatile("s_waitcnt vmcnt(0)" ::: "memory");
      }
    } else {
      if (it + 1 < nk) {
        STAGE((cur + 1) % NBUF, it + 1);
        asm volatile("s_waitcnt vmcnt(%0)" :: "n"(NLOADS) : "memory");
      } else {
        asm volatile("s_waitcnt vmcnt(0)" ::: "memory");
      }
    }
    __builtin_amdgcn_sched_barrier(0);
    __builtin_amdgcn_s_barrier();
    __builtin_amdgcn_sched_barrier(0);
    bfrag8 af[MFR], bf[NFR];
    #pragma unroll
    for (int mi = 0; mi < MFR; ++mi)
      af[mi] = *reinterpret_cast<const bfrag8*>(&As[cur][wr*WROWS + mi*16 + l16][swzrd]);
    #pragma unroll
    for (int ni = 0; ni < NFR; ++ni)
      bf[ni] = *reinterpret_cast<const bfrag8*>(&Bs[cur][wc*(TN/2) + ni*16 + l16][swzrd]);
    #pragma unroll
    for (int mi = 0; mi < MFR; ++mi)
      #pragma unroll
      for (int ni = 0; ni < NFR; ++ni)
        acc[mi][ni] = MFMA16(af[mi], bf[ni], acc[mi][ni]);
    cur = (cur + 1) % NBUF;
  }

  float* cfo = Cf;
  if constexpr (SPLITK) cfo = Cf + (size_t)blockIdx.z * (size_t)M * Nreal;
  bool dobias = !SPLITK || blockIdx.z == 0;

  #pragma unroll
  for (int mi = 0; mi < MFR; ++mi)
    #pragma unroll
    for (int ni = 0; ni < NFR; ++ni) {
      int col = n0 + wc*(TN/2) + ni*16 + l16;
      if (col >= Nreal) continue;
      float bv = dobias ? bias[col] : 0.0f;
      #pragma unroll
      for (int r2 = 0; r2 < 4; ++r2) {
        int row = m0 + wr*WROWS + mi*16 + lk*4 + r2;
        float val = acc[mi][ni][r2] + bv;
        if (ACT == 1) {
          float xx = val;
          val = 0.5f * xx * (1.0f + tanhf(0.7978845608028654f * (xx + 0.044715f * xx * xx * xx)));
        }
        size_t idx = (size_t)row * Nreal + col;
        if (OMODE == 0) cfo[idx] = val;
        else Ch[idx] = f2bf(val);
      }
    }
}

// ---------------------------------------------------------------------------
// Attention staging. K/Q: GLDS with XOR-swizzled source seg + matching read.
// ---------------------------------------------------------------------------
__device__ __forceinline__ void stage_glds64_swz(unsigned short (*dst)[64],
    const unsigned short* __restrict__ src, int ld, int t) {
  int w = t >> 6, lane = t & 63;
  int row8 = lane >> 3;
  int seg = (lane & 7) ^ (row8 & 7);
  const unsigned short* s = src + (size_t)(w*16 + row8) * ld + seg * 8;
  GLDS16(s, &dst[w*16][0]);
  GLDS16(s + (size_t)8 * ld, &dst[w*16 + 8][0]);
}

// ---------------------------------------------------------------------------
// Attention, merged sparse+global, bf16 operands, f32 online softmax (r19).
// ---------------------------------------------------------------------------
__global__ __launch_bounds__(256) void attn_kernel(
    const unsigned short* __restrict__ qkvh,
    const int* __restrict__ blk_idx, const float* __restrict__ dedup,
    const int* __restrict__ amask,
    unsigned short* __restrict__ ctxh,
    float* __restrict__ go, float* __restrict__ gm, float* __restrict__ gl) {
  __shared__ alignas(16) unsigned short Qs[64][64];
  __shared__ alignas(16) unsigned short KV2[2][64][64];
  __shared__ alignas(16) unsigned short Vs[64][66];
  __shared__ alignas(16) unsigned short Pt[64][68];
  int h = blockIdx.y;
  int bx = (int)blockIdx.x;
  const bool is_glob = (bx >= 30);
  int g = is_glob ? ((bx - 30) >> 2) : 0;
  int part = is_glob ? ((bx - 30) & 3) : 0;
  int qi = is_glob ? (g ? (NB - 1) : 0) : (bx + 1);
  int t = threadIdx.x, wave = t >> 6, lane = t & 63, l16 = lane & 15, lk = lane >> 4;
  const int swq0 = ((lk ^ (l16 & 7))) * 8;
  const int swq1 = (((4 + lk) ^ (l16 & 7))) * 8;
  const int vrow = t >> 2, vcolb = (t & 3) * 16;

  int barr[8];
  float addm[8][4];
  #pragma unroll
  for (int kb = 0; kb < 8; ++kb)
    barr[kb] = is_glob ? (part*8 + kb) : blk_idx[qi*NKB + kb];
  #pragma unroll
  for (int kb = 0; kb < 8; ++kb) {
    float dd = is_glob ? 1.0f : dedup[qi*NKB + kb];
    #pragma unroll
    for (int ni = 0; ni < 4; ++ni) {
      float mk = (float)amask[barr[kb]*64 + ni*16 + l16] * dd;
      addm[kb][ni] = (1.0f - mk) * (-1.0e9f);
    }
  }

  stage_glds64_swz(Qs, qkvh + (size_t)(qi*64)*QKVN + h*64, QKVN, t);
  __syncthreads();
  const bfrag8 q0 = *reinterpret_cast<const bfrag8*>(&Qs[wave*16 + l16][swq0]);
  const bfrag8 q1 = *reinterpret_cast<const bfrag8*>(&Qs[wave*16 + l16][swq1]);

  float mrow[4] = {-3.0e38f, -3.0e38f, -3.0e38f, -3.0e38f};
  float lrow[4] = {0.f, 0.f, 0.f, 0.f};
  facc4 o[4];
  #pragma unroll
  for (int ni = 0; ni < 4; ++ni) o[ni] = (facc4){0.f, 0.f, 0.f, 0.f};

  stage_glds64_swz(KV2[0], qkvh + (size_t)(barr[0]*64)*QKVN + DMODEL + h*64, QKVN, t);
  __builtin_amdgcn_sched_barrier(0);
  us8 vA0, vA1, vB0, vB1;
  {
    const unsigned short* vs0 = qkvh + (size_t)(barr[0]*64 + vrow)*QKVN + 2*DMODEL + h*64 + vcolb;
    vA0 = *reinterpret_cast<const us8*>(vs0);
    vA1 = *reinterpret_cast<const us8*>(vs0 + 8);
  }

  auto body = [&](int kb, const us8& vc0, const us8& vc1, us8& vn0, us8& vn1) {
    if (kb + 1 < 8) {
      int bn = barr[kb + 1];
      stage_glds64_swz(KV2[(kb + 1) & 1], qkvh + (size_t)(bn*64)*QKVN + DMODEL + h*64, QKVN, t);
      __builtin_amdgcn_sched_barrier(0);
      const unsigned short* vsn = qkvh + (size_t)(bn*64 + vrow)*QKVN + 2*DMODEL + h*64 + vcolb;
      vn0 = *reinterpret_cast<const us8*>(vsn);
      vn1 = *reinterpret_cast<const us8*>(vsn + 8);
      asm volatile("s_waitcnt vmcnt(4)" ::: "memory");
    } else {
      asm volatile("s_waitcnt vmcnt(0)" ::: "memory");
    }
    __builtin_amdgcn_sched_barrier(0);
    __builtin_amdgcn_s_barrier();
    __builtin_amdgcn_sched_barrier(0);
    float s[4][4];
    #pragma unroll
    for (int ni = 0; ni < 4; ++ni) {
      bfrag8 k0 = *reinterpret_cast<const bfrag8*>(&KV2[kb & 1][ni*16 + l16][swq0]);
      bfrag8 k1 = *reinterpret_cast<const bfrag8*>(&KV2[kb & 1][ni*16 + l16][swq1]);
      facc4 sa = (facc4){0.f, 0.f, 0.f, 0.f};
      sa = MFMA16(q0, k0, sa);
      sa = MFMA16(q1, k1, sa);
      #pragma unroll
      for (int r = 0; r < 4; ++r) s[ni][r] = sa[r] * 0.125f + addm[kb][ni];
    }
    float pexp[4][4];
    #pragma unroll
    for (int r = 0; r < 4; ++r) {
      float tm = fmaxf(fmaxf(s[0][r], s[1][r]), fmaxf(s[2][r], s[3][r]));
      tm = fmaxf(tm, __shfl_xor(tm, 1));
      tm = fmaxf(tm, __shfl_xor(tm, 2));
      tm = fmaxf(tm, __shfl_xor(tm, 4));
      tm = fmaxf(tm, __shfl_xor(tm, 8));
      float mn = fmaxf(mrow[r], tm);
      float f = expf(mrow[r] - mn);
      #pragma unroll
      for (int ni = 0; ni < 4; ++ni) o[ni][r] *= f;
      float ps = 0.0f;
      #pragma unroll
      for (int ni = 0; ni < 4; ++ni) { pexp[ni][r] = expf(s[ni][r] - mn); ps += pexp[ni][r]; }
      ps += __shfl_xor(ps, 1);
      ps += __shfl_xor(ps, 2);
      ps += __shfl_xor(ps, 4);
      ps += __shfl_xor(ps, 8);
      lrow[r] = lrow[r] * f + ps;
      mrow[r] = mn;
    }
    #pragma unroll
    for (int ni = 0; ni < 4; ++ni)
      #pragma unroll
      for (int r = 0; r < 4; ++r)
        Pt[wave*16 + lk*4 + r][ni*16 + l16] = f2bf(pexp[ni][r]);
    #pragma unroll
    for (int j = 0; j < 8; ++j) {
      Vs[vcolb + j][vrow] = vc0[j];
      Vs[vcolb + 8 + j][vrow] = vc1[j];
    }
    asm volatile("s_waitcnt lgkmcnt(0)" ::: "memory");
    __builtin_amdgcn_sched_barrier(0);
    __builtin_amdgcn_s_barrier();
    __builtin_amdgcn_sched_barrier(0);
    #pragma unroll
    for (int kc = 0; kc < 2; ++kc) {
      bfrag8 ph = *reinterpret_cast<const bfrag8*>(&Pt[wave*16 + l16][kc*32 + lk*8]);
      #pragma unroll
      for (int ni = 0; ni < 4; ++ni) {
        bfrag8 vh = *reinterpret_cast<const bfrag8*>(&Vs[ni*16 + l16][kc*32 + lk*8]);
        o[ni] = MFMA16(ph, vh, o[ni]);
      }
    }
  };

  body(0, vA0, vA1, vB0, vB1);
  body(1, vB0, vB1, vA0, vA1);
  body(2, vA0, vA1, vB0, vB1);
  body(3, vB0, vB1, vA0, vA1);
  body(4, vA0, vA1, vB0, vB1);
  body(5, vB0, vB1, vA0, vA1);
  body(6, vA0, vA1, vB0, vB1);
  body(7, vB0, vB1, vA0, vA1);

  if (!is_glob) {
    float invl[4];
    #pragma unroll
    for (int r = 0; r < 4; ++r) invl[r] = 1.0f / lrow[r];
    #pragma unroll
    for (int ni = 0; ni < 4; ++ni)
      #pragma unroll
      for (int r = 0; r < 4; ++r) {
        int row = qi*64 + wave*16 + lk*4 + r;
        int col = h*64 + ni*16 + l16;
        ctxh[(size_t)row*DMODEL + col] = f2bf(o[ni][r] * invl[r]);
      }
  } else {
    int pidx = (g * NHEAD + h) * 4 + part;
    float* gob = go + (size_t)pidx * 64 * 64;
    #pragma unroll
    for (int ni = 0; ni < 4; ++ni)
      #pragma unroll
      for (int r = 0; r < 4; ++r)
        gob[(wave*16 + lk*4 + r) * 64 + ni*16 + l16] = o[ni][r];
    if (l16 == 0) {
      #pragma unroll
      for (int r = 0; r < 4; ++r) {
        int row = wave*16 + lk*4 + r;
        gm[pidx*64 + row] = mrow[r];
        gl[pidx*64 + row] = lrow[r];
      }
    }
  }
}

__global__ __launch_bounds__(256) void gattn_comb_kernel(
    const float* __restrict__ go, const float* __restrict__ gm,
    const float* __restrict__ gl, unsigned short* __restrict__ ctxh) {
  int g = blockIdx.x, h = blockIdx.y;
  int t = threadIdx.x;
  int row = t >> 2, cseg = (t & 3) * 16;
  int base = (g * NHEAD + h) * 4;
  float m = -3.0e38f;
  for (int p = 0; p < 4; ++p) m = fmaxf(m, gm[(base + p)*64 + row]);
  float w[4]; float l = 0.0f;
  for (int p = 0; p < 4; ++p) {
    w[p] = expf(gm[(base + p)*64 + row] - m);
    l += gl[(base + p)*64 + row] * w[p];
  }
  float inv = 1.0f / l;
  int qrow = (g ? (NB - 1) * 64 : 0) + row;
  for (int c = 0; c < 16; ++c) {
    float acc = 0.0f;
    for (int p = 0; p < 4; ++p)
      acc += go[((size_t)(base + p)*64 + row)*64 + cseg + c] * w[p];
    ctxh[(size_t)qrow*DMODEL + h*64 + cseg + c] = f2bf(acc * inv);
  }
}

// ---------------------------------------------------------------------------
// Launch
// ---------------------------------------------------------------------------
extern "C" void kernel_launch(void* const* d_in, const int* in_sizes, int n_in,
                              void* d_out, int out_size, void* d_ws, size_t ws_size,
                              hipStream_t stream) {
  const int*   input_ids  = (const int*)d_in[0];
  const int*   attn_mask  = (const int*)d_in[1];
  const int*   token_type = (const int*)d_in[2];
  const float* word_emb   = (const float*)d_in[3];
  const float* pos_emb    = (const float*)d_in[4];
  const float* type_emb   = (const float*)d_in[5];
  const float* emb_ln_s   = (const float*)d_in[6];
  const float* emb_ln_b   = (const float*)d_in[7];
  const float* Wq = (const float*)d_in[8];
  const float* Wk = (const float*)d_in[9];
  const float* Wv = (const float*)d_in[10];
  const float* bq = (const float*)d_in[11];
  const float* bk = (const float*)d_in[12];
  const float* bv = (const float*)d_in[13];
  const float* Wo = (const float*)d_in[14];
  const float* bo = (const float*)d_in[15];
  const float* ln1_s = (const float*)d_in[16];
  const float* ln1_b = (const float*)d_in[17];
  const float* W1 = (const float*)d_in[18];
  const float* b1 = (const float*)d_in[19];
  const float* W2 = (const float*)d_in[20];
  const float* b2 = (const float*)d_in[21];
  const float* ln2_s = (const float*)d_in[22];
  const float* ln2_b = (const float*)d_in[23];
  const float* fc_w = (const float*)d_in[24];
  const float* fc_b = (const float*)d_in[25];
  float* out = (float*)d_out;

  unsigned char* base = (unsigned char*)d_ws;
  size_t off = 0;
  auto carve = [&](size_t bytes) -> void* {
    void* p = base + off;
    off = (off + bytes + 255) & ~(size_t)255;
    return p;
  };
  int*   blk_i = (int*)carve(256 * 4);
  float* dedup = (float*)carve(256 * 4);
  float* bqkv  = (float*)carve((size_t)NLAYER * QKVN * 4);
  float* x     = (float*)carve((size_t)S_LEN * DMODEL * 4);
  float* tmp   = (float*)carve((size_t)2 * S_LEN * DMODEL * 4);   // 2 halves for split-K
  unsigned short* xh   = (unsigned short*)carve((size_t)S_LEN * DMODEL * 2);
  unsigned short* qkvh = (unsigned short*)carve((size_t)S_LEN * QKVN * 2);
  unsigned short* ctxh = (unsigned short*)carve((size_t)S_LEN * DMODEL * 2);
  unsigned short* hbh  = (unsigned short*)carve((size_t)S_LEN * FFDIM * 2);
  float* go    = (float*)carve((size_t)2 * NHEAD * 4 * 64 * 64 * 4);
  float* gm    = (float*)carve((size_t)2 * NHEAD * 4 * 64 * 4);
  float* gl    = (float*)carve((size_t)2 * NHEAD * 4 * 64 * 4);
  unsigned short* qkvT = (unsigned short*)carve((size_t)NLAYER * QKVN * DMODEL * 2);
  unsigned short* woT  = (unsigned short*)carve((size_t)NLAYER * DMODEL * DMODEL * 2);
  unsigned short* w1T  = (unsigned short*)carve((size_t)NLAYER * FFDIM * DMODEL * 2);
  unsigned short* w2T  = (unsigned short*)carve((size_t)NLAYER * DMODEL * FFDIM * 2);
  unsigned short* fcT  = (unsigned short*)carve((size_t)VPAD * DMODEL * 2);

  blockmap_kernel<<<1, 1, 0, stream>>>(blk_i, dedup);

  const size_t DD = (size_t)DMODEL * DMODEL;
  const size_t SD = (size_t)S_LEN * DMODEL;
  dim3 g768(12, 12, NLAYER);
  tconv_kernel<<<g768, 256, 0, stream>>>(Wq, qkvT + 0,            DMODEL, DMODEL, DD, (size_t)QKVN * DMODEL);
  tconv_kernel<<<g768, 256, 0, stream>>>(Wk, qkvT + 768 * DMODEL, DMODEL, DMODEL, DD, (size_t)QKVN * DMODEL);
  tconv_kernel<<<g768, 256, 0, stream>>>(Wv, qkvT + 1536 * DMODEL,DMODEL, DMODEL, DD, (size_t)QKVN * DMODEL);
  tconv_kernel<<<g768, 256, 0, stream>>>(Wo, woT, DMODEL, DMODEL, DD, DD);
  tconv_kernel<<<dim3(48, 12, NLAYER), 256, 0, stream>>>(W1, w1T, DMODEL, FFDIM, (size_t)DMODEL * FFDIM, (size_t)FFDIM * DMODEL);
  tconv_kernel<<<dim3(12, 48, NLAYER), 256, 0, stream>>>(W2, w2T, FFDIM, DMODEL, (size_t)FFDIM * DMODEL, (size_t)DMODEL * FFDIM);
  tconv_kernel<<<dim3(VPAD / 64, 12, 1), 256, 0, stream>>>(fc_w, fcT, DMODEL, VOCAB, 0, 0);
  bias_cat_kernel<<<NLAYER, 256, 0, stream>>>(bq, bk, bv, bqkv);

  embed_ln_kernel<<<S_LEN, 256, 0, stream>>>(input_ids, token_type, word_emb, pos_emb,
                                             type_emb, emb_ln_s, emb_ln_b, x, xh);

  for (int l = 0; l < NLAYER; ++l) {
    gemm16_kernel<64, 4, 128, 2, 0, 0, 4><<<dim3(32, QKVN/128), 256, 0, stream>>>(
        xh, qkvT + (size_t)l * QKVN * DMODEL, bqkv + (size_t)l * QKVN,
        nullptr, qkvh, DMODEL, QKVN, DMODEL, S_LEN);

    attn_kernel<<<dim3(38, NHEAD), 256, 0, stream>>>(
        qkvh, blk_i, dedup, attn_mask, ctxh, go, gm, gl);
    gattn_comb_kernel<<<dim3(2, NHEAD), 256, 0, stream>>>(go, gm, gl, ctxh);

    // Wo: split-K x2 -> partials tmp[0..SD), tmp[SD..2SD)
    gemm16_kernel<64, 4, 64, 0, 0, 1, 4><<<dim3(32, DMODEL/64, 2), 256, 0, stream>>>(
        ctxh, woT + (size_t)l * DD, bo + (size_t)l * DMODEL,
        tmp, nullptr, DMODEL/2, DMODEL, DMODEL, S_LEN);
    resln3_kernel<<<S_LEN, 256, 0, stream>>>(x, tmp, tmp + SD,
                                             ln1_s + l*DMODEL, ln1_b + l*DMODEL, xh);

    gemm16_kernel<64, 4, 128, 2, 1, 0, 4><<<dim3(32, FFDIM/128), 256, 0, stream>>>(
        xh, w1T + (size_t)l * FFDIM * DMODEL, b1 + (size_t)l * FFDIM,
        nullptr, hbh, DMODEL, FFDIM, DMODEL, S_LEN);
    // FF2: split-K x2 -> partials tmp[0..SD), tmp[SD..2SD)
    gemm16_kernel<64, 4, 64, 0, 0, 1, 4><<<dim3(32, DMODEL/64, 2), 256, 0, stream>>>(
        hbh, w2T + (size_t)l * DMODEL * FFDIM, b2 + (size_t)l * DMODEL,
        tmp, nullptr, FFDIM/2, DMODEL, FFDIM, S_LEN);
    resln3_kernel<<<S_LEN, 256, 0, stream>>>(x, tmp, tmp + SD,
                                             ln2_s + l*DMODEL, ln2_b + l*DMODEL, xh);
  }

  // Vocab: 512-thread, BM=256 x TN=128, NBUF=3 -> 72KB LDS, 2 blk/CU = 16 waves
  gemm16_kernel<256, 3, 128, 0, 0, 0, 8><<<dim3(8, VPAD/128), 512, 0, stream>>>(
      xh, fcT, fc_b, out, nullptr, DMODEL, VOCAB, DMODEL, S_LEN);
}